// Round 8
// baseline (340.103 us; speedup 1.0000x reference)
//
#include <hip/hip_runtime.h>
#include <math.h>

constexpr int CL = 256;
constexpr int CD = 768;
constexpr int CATT = 100;
constexpr int CH = 5;
constexpr int CDK = 20;

__device__ __forceinline__ void fma4(float4& a, float s, const float4& w) {
    a.x = fmaf(s, w.x, a.x);
    a.y = fmaf(s, w.y, a.y);
    a.z = fmaf(s, w.z, a.z);
    a.w = fmaf(s, w.w, a.w);
}

// Per-batch flag sync. Produce-before-consume ordering makes this deadlock-free
// regardless of residency; with 512 blocks <= capacity it is also fast.
__device__ __forceinline__ void signal_done(int* ctr, int t) {
    __syncthreads();   // drain this block's stores (compiler emits vmcnt(0))
    if (t == 0)
        __hip_atomic_fetch_add(ctr, 1, __ATOMIC_RELEASE, __HIP_MEMORY_SCOPE_AGENT);
}
__device__ __forceinline__ void spin_wait(int* ctr, int target, int t) {
    if (t == 0) {
        while (__hip_atomic_load(ctr, __ATOMIC_ACQUIRE, __HIP_MEMORY_SCOPE_AGENT) < target)
            __builtin_amdgcn_s_sleep(2);
    }
    __syncthreads();
}

struct SMem {
    float w[2][3200];    // 25.6KB staging (W / g / go1 tiles)
    float adjW[4160];    // written phase1, read phase2 -- never touches HBM
    float pool[4160];    // p0: gt+ln; p1: adjS then ax; p2: ax + part sums
    float q[1600];       // p0: xn dbuf, then q fragments (LDS-resident to p1)
    float red[5][64];
    float m[256];        // amask
    float asp[100];      // masked g sums; p3: pooled out1
    float aspb[20], was[5];
    float w1[100], w2[100];
    float gw1[256], gw2[256];
    float t1v[100], t2v[100];
    float mean[16], rinv[16];
    float wnv;
};

__global__ __launch_bounds__(256) void k_fused(
    const float* __restrict__ x, const float* __restrict__ ln_a,
    const float* __restrict__ ln_b, const float* __restrict__ Wxx_w,
    const float* __restrict__ Wxx_b, const float* __restrict__ q_w,
    const float* __restrict__ q_b, const float* __restrict__ k_w,
    const float* __restrict__ k_b, const float* __restrict__ amask,
    const int* __restrict__ src_mask, const float* __restrict__ shortm,
    const float* __restrict__ dense_w, const float* __restrict__ dense_b,
    const float* __restrict__ bias_m, const float* __restrict__ Wx_w,
    const float* __restrict__ Wx_b, const float* __restrict__ W_w,
    const float* __restrict__ W_b, const float* __restrict__ clf_w,
    const float* __restrict__ clf_b, float* __restrict__ g,
    float* __restrict__ ktb, float* __restrict__ go1,
    float* __restrict__ out1_part, int* __restrict__ done,
    float* __restrict__ out)
{
    __shared__ SMem sm;
    const int t = threadIdx.x;
    const int blk = blockIdx.x;
    const int b = blk >> 4, ic = blk & 15;
    const int i0 = ic * 16;
    const int cg2 = t % 25, rg = t / 25;
    const int c = cg2 * 4;
    const int lane = t & 63, wid = t >> 6;

    //========================= PHASE 0: LN + g + q/k =========================
    {
        const int r0 = blk * 16;
        float* s_gt = sm.pool;
        float* s_ln = sm.pool + 1600;
        float* s_xn0 = sm.q;
        float* s_xn1 = sm.q + 576;

        if (t < 192) {
            ((float4*)s_ln)[t] = ((const float4*)ln_a)[t];
            ((float4*)(s_ln + 768))[t] = ((const float4*)ln_b)[t];
        }
        for (int rr = wid * 4; rr < wid * 4 + 4; ++rr) {
            const float* xr = x + (size_t)(r0 + rr) * CD;
            float xv[12];
            float s = 0.f;
#pragma unroll
            for (int m2 = 0; m2 < 12; ++m2) { xv[m2] = xr[lane + 64 * m2]; s += xv[m2]; }
#pragma unroll
            for (int o = 32; o; o >>= 1) s += __shfl_xor(s, o);
            float mean = s * (1.0f / 768.0f);
            float sq = 0.f;
#pragma unroll
            for (int m2 = 0; m2 < 12; ++m2) { float d = xv[m2] - mean; sq = fmaf(d, d, sq); }
#pragma unroll
            for (int o = 32; o; o >>= 1) sq += __shfl_xor(sq, o);
            if (lane == 0) {
                sm.mean[rr] = mean;
                sm.rinv[rr] = 1.0f / (sqrtf(sq * (1.0f / 767.0f)) + 1e-6f);
            }
        }

        const float4* wsrc = (const float4*)Wxx_w;
        float4 w0 = wsrc[t], w1 = wsrc[t + 256], w2 = wsrc[t + 512], w3;
        if (t < 32) w3 = wsrc[t + 768];
        const int rA = t >> 5, cA = t & 31;
        float xa = x[(size_t)(r0 + rA) * CD + cA];
        float xb = x[(size_t)(r0 + rA + 8) * CD + cA];

        __syncthreads();

        {
            float4* d4 = (float4*)sm.w[0];
            d4[t] = w0; d4[t + 256] = w1; d4[t + 512] = w2;
            if (t < 32) d4[t + 768] = w3;
            float la = s_ln[cA], lbv = s_ln[768 + cA];
            s_xn0[rA * 36 + cA] = fmaf(la, (xa - sm.mean[rA]) * sm.rinv[rA], lbv);
            s_xn0[(rA + 8) * 36 + cA] = fmaf(la, (xb - sm.mean[rA + 8]) * sm.rinv[rA + 8], lbv);
        }
        __syncthreads();

        float4 acc0 = make_float4(0.f, 0.f, 0.f, 0.f);
        float4 acc1 = make_float4(0.f, 0.f, 0.f, 0.f);

        for (int kt = 0; kt < 24; ++kt) {
            if (kt < 23) {
                const float4* ws = wsrc + (size_t)(kt + 1) * 800;
                w0 = ws[t]; w1 = ws[t + 256]; w2 = ws[t + 512];
                if (t < 32) w3 = ws[t + 768];
                int gc = (kt + 1) * 32 + cA;
                xa = x[(size_t)(r0 + rA) * CD + gc];
                xb = x[(size_t)(r0 + rA + 8) * CD + gc];
            }
            if (t < 200) {
                const float* wb = sm.w[kt & 1];
                const float* xbuf = (kt & 1) ? s_xn1 : s_xn0;
#pragma unroll 2
                for (int kk = 0; kk < 32; kk += 4) {
                    float4 a0 = *(const float4*)&xbuf[(rg * 2 + 0) * 36 + kk];
                    float4 a1 = *(const float4*)&xbuf[(rg * 2 + 1) * 36 + kk];
                    float4 v0 = *(const float4*)&wb[(kk + 0) * 100 + c];
                    float4 v1 = *(const float4*)&wb[(kk + 1) * 100 + c];
                    float4 v2 = *(const float4*)&wb[(kk + 2) * 100 + c];
                    float4 v3 = *(const float4*)&wb[(kk + 3) * 100 + c];
                    fma4(acc0, a0.x, v0); fma4(acc0, a0.y, v1); fma4(acc0, a0.z, v2); fma4(acc0, a0.w, v3);
                    fma4(acc1, a1.x, v0); fma4(acc1, a1.y, v1); fma4(acc1, a1.z, v2); fma4(acc1, a1.w, v3);
                }
            }
            if (kt < 23) {
                float4* d4 = (float4*)sm.w[(kt + 1) & 1];
                d4[t] = w0; d4[t + 256] = w1; d4[t + 512] = w2;
                if (t < 32) d4[t + 768] = w3;
                int gc = (kt + 1) * 32 + cA;
                float la = s_ln[gc], lbv = s_ln[768 + gc];
                float* xd = ((kt + 1) & 1) ? s_xn1 : s_xn0;
                xd[rA * 36 + cA] = fmaf(la, (xa - sm.mean[rA]) * sm.rinv[rA], lbv);
                xd[(rA + 8) * 36 + cA] = fmaf(la, (xb - sm.mean[rA + 8]) * sm.rinv[rA + 8], lbv);
            }
            __syncthreads();
        }

        if (t < 200) {
            float4 bias = *(const float4*)&Wxx_b[c];
            float4 rv0, rv1;
            rv0.x = acc0.x + bias.x; rv0.y = acc0.y + bias.y; rv0.z = acc0.z + bias.z; rv0.w = acc0.w + bias.w;
            rv1.x = acc1.x + bias.x; rv1.y = acc1.y + bias.y; rv1.z = acc1.z + bias.z; rv1.w = acc1.w + bias.w;
            float4 rv[2] = { rv0, rv1 };
#pragma unroll
            for (int q = 0; q < 2; ++q) {
                int row = r0 + rg * 2 + q;
                *(float4*)&g[(size_t)row * CATT + c] = rv[q];
                *(float4*)&s_gt[(rg * 2 + q) * 100 + c] = rv[q];
            }
        }

        // q/k GEMMs: q fragments stay in LDS (sm.q); k -> global ktb
        const float4* qw4 = (const float4*)q_w;
        const float4* kw4 = (const float4*)k_w;
        float4 sA = qw4[t], sB;
        if (t < 244) sB = qw4[t + 256];
        __syncthreads();
        {
            float4* d4 = (float4*)sm.w[0];
            d4[t] = sA; if (t < 244) d4[t + 256] = sB;
        }
        __syncthreads();

        float4 p0 = make_float4(0.f, 0.f, 0.f, 0.f);
        float4 p1 = make_float4(0.f, 0.f, 0.f, 0.f);
        for (int tau = 0; tau < 10; ++tau) {
            if (tau < 9) {
                const float4* src = (tau + 1 < 5) ? qw4 + (size_t)(tau + 1) * 500
                                                  : kw4 + (size_t)(tau - 4) * 500;
                sA = src[t]; if (t < 244) sB = src[t + 256];
            }
            if (t < 200) {
                const float* wb = sm.w[tau & 1];
                const int kb = (tau % 5) * 20;
#pragma unroll 2
                for (int kk = 0; kk < 20; kk += 4) {
                    float4 a0 = *(const float4*)&s_gt[(rg * 2 + 0) * 100 + kb + kk];
                    float4 a1 = *(const float4*)&s_gt[(rg * 2 + 1) * 100 + kb + kk];
                    float4 v0 = *(const float4*)&wb[(kk + 0) * 100 + c];
                    float4 v1 = *(const float4*)&wb[(kk + 1) * 100 + c];
                    float4 v2 = *(const float4*)&wb[(kk + 2) * 100 + c];
                    float4 v3 = *(const float4*)&wb[(kk + 3) * 100 + c];
                    fma4(p0, a0.x, v0); fma4(p0, a0.y, v1); fma4(p0, a0.z, v2); fma4(p0, a0.w, v3);
                    fma4(p1, a1.x, v0); fma4(p1, a1.y, v1); fma4(p1, a1.z, v2); fma4(p1, a1.w, v3);
                }
                if (tau == 4) {
                    float4 bias = *(const float4*)&q_b[c];
                    const int h = c / CDK, d = c % CDK;
#pragma unroll
                    for (int q = 0; q < 2; ++q) {
                        float4 r = (q == 0) ? p0 : p1;
                        r.x += bias.x; r.y += bias.y; r.z += bias.z; r.w += bias.w;
                        *(float4*)&sm.q[h * 320 + (rg * 2 + q) * CDK + d] = r;
                    }
                    p0 = make_float4(0.f, 0.f, 0.f, 0.f);
                    p1 = make_float4(0.f, 0.f, 0.f, 0.f);
                } else if (tau == 9) {
                    float4 bias = *(const float4*)&k_b[c];
                    const int h = c / CDK, d = c % CDK;
#pragma unroll
                    for (int q = 0; q < 2; ++q) {
                        float4 r = (q == 0) ? p0 : p1;
                        r.x += bias.x; r.y += bias.y; r.z += bias.z; r.w += bias.w;
                        int l = i0 + rg * 2 + q;
                        *(float4*)&ktb[((size_t)(b * CH + h) * CL + l) * CDK + d] = r;
                    }
                }
            }
            if (tau < 9) {
                float4* d4 = (float4*)sm.w[(tau + 1) & 1];
                d4[t] = sA; if (t < 244) d4[t + 256] = sB;
            }
            __syncthreads();
        }
    }
    signal_done(&done[b], t);          // g + ktb of this chunk published

    //================= PHASE 1: asp + softmax + GCN0 =========================
    {
        constexpr int ICH = 16;
        spin_wait(&done[b], 16, t);    // all g/ktb rows of batch b ready

        if (t < 64) {
            float4 mv = ((const float4*)amask)[b * 64 + t];
            *(float4*)&sm.m[t * 4] = mv;
            float wn = mv.x + mv.y + mv.z + mv.w;
#pragma unroll
            for (int o = 32; o; o >>= 1) wn += __shfl_xor(wn, o);
            if (t == 0) sm.wnv = wn;
        }
        if (t < 5) {
            float s = 0.f;
            for (int k2 = 0; k2 < 5; ++k2) s += Wx_w[t * 5 + k2];
            sm.was[t] = s;
        }
        float smv[ICH];
#pragma unroll
        for (int ii = 0; ii < ICH; ++ii)
            smv[ii] = shortm[(size_t)(b * CL + i0 + ii) * CL + t];
        __syncthreads();

        if (t < 100) {   // masked aspect pooling from g (mask is ~4 nonzeros)
            float a = 0.f;
            for (int l = 0; l < CL; ++l) {
                float m = sm.m[l];
                if (m != 0.f) a = fmaf(m, g[(size_t)(b * CL + l) * CATT + t], a);
            }
            sm.asp[t] = a;
        }
        __syncthreads();
        if (t < 20) {
            float a = 0.f;
            for (int d = 0; d < CATT; ++d)
                a = fmaf(sm.asp[d], dense_w[d * CDK + t], a);
            sm.aspb[t] = a / sm.wnv + dense_b[t];
        }
        __syncthreads();

        const bool masked = (src_mask[b * CL + t] == 0);
        const float bm = bias_m[0];
        const float rs20 = 0.223606797749978969f;
        const int j = t;

        float accS[ICH], accW[ICH];
#pragma unroll
        for (int ii = 0; ii < ICH; ++ii) { accS[ii] = 0.f; accW[ii] = 0.f; }

        for (int h = 0; h < CH; ++h) {
            float4 kr[5];
            const float* kp = ktb + ((size_t)(b * CH + h) * CL + j) * CDK;
#pragma unroll
            for (int m2 = 0; m2 < 5; ++m2) kr[m2] = *(const float4*)(kp + 4 * m2);
            const float was_h = sm.was[h];
            float s = bm;
#pragma unroll
            for (int m2 = 0; m2 < 5; ++m2) {
                s = fmaf(sm.aspb[4 * m2 + 0], kr[m2].x, s);
                s = fmaf(sm.aspb[4 * m2 + 1], kr[m2].y, s);
                s = fmaf(sm.aspb[4 * m2 + 2], kr[m2].z, s);
                s = fmaf(sm.aspb[4 * m2 + 3], kr[m2].w, s);
            }
            const float aspsc = tanhf(s);

            float pv[ICH];
#pragma unroll
            for (int ii = 0; ii < ICH; ++ii) {
                const float* qrow = &sm.q[h * 320 + ii * CDK];
                float sc = 0.f;
#pragma unroll
                for (int m2 = 0; m2 < 5; ++m2) {
                    float4 q4 = *(const float4*)(qrow + 4 * m2);
                    sc = fmaf(q4.x, kr[m2].x, sc);
                    sc = fmaf(q4.y, kr[m2].y, sc);
                    sc = fmaf(q4.z, kr[m2].z, sc);
                    sc = fmaf(q4.w, kr[m2].w, sc);
                }
                sc = fmaf(sc, rs20, aspsc) + smv[ii];
                float p = masked ? 0.f : __expf(sc);
                pv[ii] = p;
                float ssum = p;
#pragma unroll
                for (int o = 32; o; o >>= 1) ssum += __shfl_xor(ssum, o);
                if (lane == 0) sm.red[h][ii * 4 + wid] = ssum;
            }
            __syncthreads();
#pragma unroll
            for (int ii = 0; ii < ICH; ++ii) {
                float tot = sm.red[h][ii * 4 + 0] + sm.red[h][ii * 4 + 1] +
                            sm.red[h][ii * 4 + 2] + sm.red[h][ii * 4 + 3];
                float pn = pv[ii] * __frcp_rn(tot);
                accS[ii] += pn;
                accW[ii] = fmaf(was_h, pn, accW[ii]);
            }
        }

#pragma unroll
        for (int ii = 0; ii < ICH; ++ii) {
            sm.adjW[ii * 260 + j] = accW[ii];   // LDS-resident until phase 2
            sm.pool[ii * 260 + j] = accS[ii];
        }

        // GEMM1: Ax = adjS @ g
        const float4* g4 = (const float4*)g + (size_t)b * 6400;
        float4 sA = g4[t], sB = g4[t + 256], sC = g4[t + 512], sD;
        if (t < 32) sD = g4[t + 768];
        {
            float4* d4 = (float4*)sm.w[0];
            d4[t] = sA; d4[t + 256] = sB; d4[t + 512] = sC;
            if (t < 32) d4[t + 768] = sD;
        }
        __syncthreads();

        float4 acc0 = make_float4(0.f, 0.f, 0.f, 0.f);
        float4 acc1 = make_float4(0.f, 0.f, 0.f, 0.f);
        for (int jt = 0; jt < 8; ++jt) {
            if (jt < 7) {
                const float4* src = g4 + (size_t)(jt + 1) * 800;
                sA = src[t]; sB = src[t + 256]; sC = src[t + 512];
                if (t < 32) sD = src[t + 768];
            }
            if (t < 200) {
                const float* wb = sm.w[jt & 1];
#pragma unroll 2
                for (int kk = 0; kk < 32; kk += 4) {
                    float4 a0 = *(const float4*)&sm.pool[(rg * 2 + 0) * 260 + jt * 32 + kk];
                    float4 a1 = *(const float4*)&sm.pool[(rg * 2 + 1) * 260 + jt * 32 + kk];
                    float4 v0 = *(const float4*)&wb[(kk + 0) * 100 + c];
                    float4 v1 = *(const float4*)&wb[(kk + 1) * 100 + c];
                    float4 v2 = *(const float4*)&wb[(kk + 2) * 100 + c];
                    float4 v3 = *(const float4*)&wb[(kk + 3) * 100 + c];
                    fma4(acc0, a0.x, v0); fma4(acc0, a0.y, v1); fma4(acc0, a0.z, v2); fma4(acc0, a0.w, v3);
                    fma4(acc1, a1.x, v0); fma4(acc1, a1.y, v1); fma4(acc1, a1.z, v2); fma4(acc1, a1.w, v3);
                }
            }
            if (jt < 7) {
                float4* d4 = (float4*)sm.w[(jt + 1) & 1];
                d4[t] = sA; d4[t + 256] = sB; d4[t + 512] = sC;
                if (t < 32) d4[t + 768] = sD;
            }
            __syncthreads();
        }

        float* s_ax = sm.pool;
        if (t < 200) {
            float4 r;
            r.x = acc0.x * 0.2f; r.y = acc0.y * 0.2f; r.z = acc0.z * 0.2f; r.w = acc0.w * 0.2f;
            *(float4*)&s_ax[(rg * 2 + 0) * 108 + c] = r;
            r.x = acc1.x * 0.2f; r.y = acc1.y * 0.2f; r.z = acc1.z * 0.2f; r.w = acc1.w * 0.2f;
            *(float4*)&s_ax[(rg * 2 + 1) * 108 + c] = r;
        }
        const float4* ww4 = (const float4*)W_w;
        sA = ww4[t]; if (t < 244) sB = ww4[t + 256];
        {
            float4* d4 = (float4*)sm.w[0];
            d4[t] = sA; if (t < 244) d4[t + 256] = sB;
        }
        __syncthreads();

        float4 o0 = make_float4(0.f, 0.f, 0.f, 0.f);
        float4 o1 = make_float4(0.f, 0.f, 0.f, 0.f);
        for (int wt = 0; wt < 5; ++wt) {
            if (wt < 4) {
                const float4* src = ww4 + (size_t)(wt + 1) * 500;
                sA = src[t]; if (t < 244) sB = src[t + 256];
            }
            if (t < 200) {
                const float* wb = sm.w[wt & 1];
                const int kb = wt * 20;
#pragma unroll 2
                for (int kk = 0; kk < 20; kk += 4) {
                    float4 a0 = *(const float4*)&s_ax[(rg * 2 + 0) * 108 + kb + kk];
                    float4 a1 = *(const float4*)&s_ax[(rg * 2 + 1) * 108 + kb + kk];
                    float4 v0 = *(const float4*)&wb[(kk + 0) * 100 + c];
                    float4 v1 = *(const float4*)&wb[(kk + 1) * 100 + c];
                    float4 v2 = *(const float4*)&wb[(kk + 2) * 100 + c];
                    float4 v3 = *(const float4*)&wb[(kk + 3) * 100 + c];
                    fma4(o0, a0.x, v0); fma4(o0, a0.y, v1); fma4(o0, a0.z, v2); fma4(o0, a0.w, v3);
                    fma4(o1, a1.x, v0); fma4(o1, a1.y, v1); fma4(o1, a1.z, v2); fma4(o1, a1.w, v3);
                }
            }
            if (wt < 4) {
                float4* d4 = (float4*)sm.w[(wt + 1) & 1];
                d4[t] = sA; if (t < 244) d4[t + 256] = sB;
            }
            __syncthreads();
        }

        if (t < 200) {
            float4 bias = *(const float4*)&W_b[c];
            o0.x = fmaxf(o0.x + bias.x, 0.f); o0.y = fmaxf(o0.y + bias.y, 0.f);
            o0.z = fmaxf(o0.z + bias.z, 0.f); o0.w = fmaxf(o0.w + bias.w, 0.f);
            o1.x = fmaxf(o1.x + bias.x, 0.f); o1.y = fmaxf(o1.y + bias.y, 0.f);
            o1.z = fmaxf(o1.z + bias.z, 0.f); o1.w = fmaxf(o1.w + bias.w, 0.f);
            *(float4*)&go1[(size_t)(b * CL + i0 + rg * 2 + 0) * CATT + c] = o0;
            *(float4*)&go1[(size_t)(b * CL + i0 + rg * 2 + 1) * CATT + c] = o1;
        }
    }
    signal_done(&done[32 + b], t);     // go1 rows of this chunk published

    //================== PHASE 2: rank-1 + GCN1 + pooling =====================
    {
        spin_wait(&done[32 + b], 16, t);

        if (t < 100) {
            float a = 0.f, c2 = 0.f;
#pragma unroll
            for (int h = 0; h < 5; ++h) {
                a += Wx_w[(5 + t) * 5 + h];
                c2 += Wx_w[(105 + t) * 5 + h];
            }
            sm.w1[t] = a; sm.w2[t] = c2;
        }
        __syncthreads();
        {   // per-row dots gw1/gw2 for all 256 rows of batch b
            const float* rp = go1 + (size_t)(b * CL + t) * CATT;
            float a = 0.f, c2 = 0.f;
            for (int e = 0; e < 100; ++e) {
                float v = rp[e];
                a = fmaf(v, sm.w1[e], a);
                c2 = fmaf(v, sm.w2[e], c2);
            }
            sm.gw1[t] = a; sm.gw2[t] = c2;
        }
        __syncthreads();
        if (t < 100) {   // t1/t2 reductions over all rows
            float a = 0.f, s2 = 0.f;
            for (int j2 = 0; j2 < CL; ++j2) {
                float v = go1[(size_t)(b * CL + j2) * CATT + t];
                a = fmaf(sm.gw1[j2], v, a);
                s2 += v;
            }
            sm.t1v[t] = a; sm.t2v[t] = s2;
        }
        __syncthreads();

        // GEMM1: adjW(LDS) @ go1
        const float4* g4 = (const float4*)go1 + (size_t)b * 6400;
        float4 sA = g4[t], sB = g4[t + 256], sC = g4[t + 512], sD;
        if (t < 32) sD = g4[t + 768];
        {
            float4* d4 = (float4*)sm.w[0];
            d4[t] = sA; d4[t + 256] = sB; d4[t + 512] = sC;
            if (t < 32) d4[t + 768] = sD;
        }
        __syncthreads();

        float4 acc0 = make_float4(0.f, 0.f, 0.f, 0.f);
        float4 acc1 = make_float4(0.f, 0.f, 0.f, 0.f);
        for (int jt = 0; jt < 8; ++jt) {
            if (jt < 7) {
                const float4* src = g4 + (size_t)(jt + 1) * 800;
                sA = src[t]; sB = src[t + 256]; sC = src[t + 512];
                if (t < 32) sD = src[t + 768];
            }
            if (t < 200) {
                const float* wb = sm.w[jt & 1];
#pragma unroll 2
                for (int kk = 0; kk < 32; kk += 4) {
                    float4 a0 = *(const float4*)&sm.adjW[(rg * 2 + 0) * 260 + jt * 32 + kk];
                    float4 a1 = *(const float4*)&sm.adjW[(rg * 2 + 1) * 260 + jt * 32 + kk];
                    float4 v0 = *(const float4*)&wb[(kk + 0) * 100 + c];
                    float4 v1 = *(const float4*)&wb[(kk + 1) * 100 + c];
                    float4 v2 = *(const float4*)&wb[(kk + 2) * 100 + c];
                    float4 v3 = *(const float4*)&wb[(kk + 3) * 100 + c];
                    fma4(acc0, a0.x, v0); fma4(acc0, a0.y, v1); fma4(acc0, a0.z, v2); fma4(acc0, a0.w, v3);
                    fma4(acc1, a1.x, v0); fma4(acc1, a1.y, v1); fma4(acc1, a1.z, v2); fma4(acc1, a1.w, v3);
                }
            }
            if (jt < 7) {
                float4* d4 = (float4*)sm.w[(jt + 1) & 1];
                d4[t] = sA; d4[t + 256] = sB; d4[t + 512] = sC;
                if (t < 32) d4[t + 768] = sD;
            }
            __syncthreads();
        }

        float* s_ax = sm.pool;
        if (t < 200) {
            float wxbs = Wx_b[0] + Wx_b[1] + Wx_b[2] + Wx_b[3] + Wx_b[4];
            float4 t1v = *(const float4*)&sm.t1v[c];
            float4 t2v = *(const float4*)&sm.t2v[c];
            float gw0 = sm.gw2[i0 + rg * 2 + 0] + wxbs;
            float gw1v = sm.gw2[i0 + rg * 2 + 1] + wxbs;
            float4 r;
            r.x = (acc0.x + t1v.x + gw0 * t2v.x) * 0.2f;
            r.y = (acc0.y + t1v.y + gw0 * t2v.y) * 0.2f;
            r.z = (acc0.z + t1v.z + gw0 * t2v.z) * 0.2f;
            r.w = (acc0.w + t1v.w + gw0 * t2v.w) * 0.2f;
            *(float4*)&s_ax[(rg * 2 + 0) * 108 + c] = r;
            r.x = (acc1.x + t1v.x + gw1v * t2v.x) * 0.2f;
            r.y = (acc1.y + t1v.y + gw1v * t2v.y) * 0.2f;
            r.z = (acc1.z + t1v.z + gw1v * t2v.z) * 0.2f;
            r.w = (acc1.w + t1v.w + gw1v * t2v.w) * 0.2f;
            *(float4*)&s_ax[(rg * 2 + 1) * 108 + c] = r;
        }
        const float4* ww4 = (const float4*)W_w;
        sA = ww4[t]; if (t < 244) sB = ww4[t + 256];
        {
            float4* d4 = (float4*)sm.w[0];
            d4[t] = sA; if (t < 244) d4[t + 256] = sB;
        }
        __syncthreads();

        float4 o0 = make_float4(0.f, 0.f, 0.f, 0.f);
        float4 o1 = make_float4(0.f, 0.f, 0.f, 0.f);
        for (int wt = 0; wt < 5; ++wt) {
            if (wt < 4) {
                const float4* src = ww4 + (size_t)(wt + 1) * 500;
                sA = src[t]; if (t < 244) sB = src[t + 256];
            }
            if (t < 200) {
                const float* wb = sm.w[wt & 1];
                const int kb = wt * 20;
#pragma unroll 2
                for (int kk = 0; kk < 20; kk += 4) {
                    float4 a0 = *(const float4*)&s_ax[(rg * 2 + 0) * 108 + kb + kk];
                    float4 a1 = *(const float4*)&s_ax[(rg * 2 + 1) * 108 + kb + kk];
                    float4 v0 = *(const float4*)&wb[(kk + 0) * 100 + c];
                    float4 v1 = *(const float4*)&wb[(kk + 1) * 100 + c];
                    float4 v2 = *(const float4*)&wb[(kk + 2) * 100 + c];
                    float4 v3 = *(const float4*)&wb[(kk + 3) * 100 + c];
                    fma4(o0, a0.x, v0); fma4(o0, a0.y, v1); fma4(o0, a0.z, v2); fma4(o0, a0.w, v3);
                    fma4(o1, a1.x, v0); fma4(o1, a1.y, v1); fma4(o1, a1.z, v2); fma4(o1, a1.w, v3);
                }
            }
            if (wt < 4) {
                float4* d4 = (float4*)sm.w[(wt + 1) & 1];
                d4[t] = sA; if (t < 244) d4[t + 256] = sB;
            }
            __syncthreads();
        }

        // masked pooled partials (deterministic stores, no atomics)
        float* s_part = sm.pool + 1728;   // 8 x 100
        if (t < 200) {
            float4 bias = *(const float4*)&W_b[c];
            o0.x = fmaxf(o0.x + bias.x, 0.f); o0.y = fmaxf(o0.y + bias.y, 0.f);
            o0.z = fmaxf(o0.z + bias.z, 0.f); o0.w = fmaxf(o0.w + bias.w, 0.f);
            o1.x = fmaxf(o1.x + bias.x, 0.f); o1.y = fmaxf(o1.y + bias.y, 0.f);
            o1.z = fmaxf(o1.z + bias.z, 0.f); o1.w = fmaxf(o1.w + bias.w, 0.f);
            float m0 = amask[b * CL + i0 + rg * 2 + 0];
            float m1 = amask[b * CL + i0 + rg * 2 + 1];
            float4 pr;
            pr.x = m0 * o0.x + m1 * o1.x;
            pr.y = m0 * o0.y + m1 * o1.y;
            pr.z = m0 * o0.z + m1 * o1.z;
            pr.w = m0 * o0.w + m1 * o1.w;
            *(float4*)&s_part[rg * 100 + c] = pr;
        }
        __syncthreads();
        if (t < 100) {
            float s2 = 0.f;
#pragma unroll
            for (int r = 0; r < 8; ++r) s2 += s_part[r * 100 + t];
            out1_part[(size_t)(b * 16 + ic) * CATT + t] = s2;
        }
    }
    signal_done(&done[64 + b], t);

    //========================= PHASE 3: classifier ===========================
    if (ic == 0) {
        spin_wait(&done[64 + b], 16, t);
        if (t < 64) {
            float4 mv = ((const float4*)amask)[b * 64 + t];
            float wn = mv.x + mv.y + mv.z + mv.w;
#pragma unroll
            for (int o = 32; o; o >>= 1) wn += __shfl_xor(wn, o);
            if (t == 0) sm.wnv = wn;
        }
        __syncthreads();
        if (t < 100) {
            float s2 = 0.f;
#pragma unroll
            for (int c2 = 0; c2 < 16; ++c2)
                s2 += out1_part[(size_t)(b * 16 + c2) * CATT + t];
            sm.asp[t] = s2 / sm.wnv;
        }
        __syncthreads();
        if (t < 3) {
            float a = clf_b[t];
            for (int d = 0; d < CATT; ++d)
                a = fmaf(sm.asp[d], clf_w[d * 3 + t], a);
            out[b * 3 + t] = a;
        }
    }
}

// ---------------------------------------------------------------------------
extern "C" void kernel_launch(void* const* d_in, const int* in_sizes, int n_in,
                              void* d_out, int out_size, void* d_ws, size_t ws_size,
                              hipStream_t stream) {
    const float* seq     = (const float*)d_in[0];
    const int*   srcm    = (const int*)d_in[1];
    const float* amask   = (const float*)d_in[2];
    const float* shortm  = (const float*)d_in[3];
    const float* ln_a    = (const float*)d_in[4];
    const float* ln_b    = (const float*)d_in[5];
    const float* Wxx_w   = (const float*)d_in[6];
    const float* Wxx_b   = (const float*)d_in[7];
    const float* q_w     = (const float*)d_in[8];
    const float* q_b     = (const float*)d_in[9];
    const float* k_w     = (const float*)d_in[10];
    const float* k_b     = (const float*)d_in[11];
    const float* dense_w = (const float*)d_in[12];
    const float* dense_b = (const float*)d_in[13];
    const float* bias_m  = (const float*)d_in[14];
    const float* W_w     = (const float*)d_in[15];
    const float* W_b     = (const float*)d_in[16];
    const float* Wx_w    = (const float*)d_in[17];
    const float* Wx_b    = (const float*)d_in[18];
    const float* clf_w   = (const float*)d_in[19];
    const float* clf_b   = (const float*)d_in[20];
    float* out = (float*)d_out;

    float* ws        = (float*)d_ws;
    float* g         = ws;                  // 819200
    float* ktb       = g + 819200;          // 819200
    float* go1       = ktb + 819200;        // 819200
    float* out1_part = go1 + 819200;        // 51200
    int*   done      = (int*)(out1_part + 51200);   // 96 ints

    hipMemsetAsync(done, 0, 96 * sizeof(int), stream);
    hipLaunchKernelGGL(k_fused, dim3(512), dim3(256), 0, stream,
                       seq, ln_a, ln_b, Wxx_w, Wxx_b, q_w, q_b, k_w, k_b,
                       amask, srcm, shortm, dense_w, dense_b, bias_m,
                       Wx_w, Wx_b, W_w, W_b, clf_w, clf_b,
                       g, ktb, go1, out1_part, done, out);
}

// Round 9
// 257.653 us; speedup vs baseline: 1.3200x; 1.3200x over previous
//
#include <hip/hip_runtime.h>
#include <math.h>

constexpr int CL = 256;
constexpr int CD = 768;
constexpr int CATT = 100;
constexpr int CH = 5;
constexpr int CDK = 20;

__device__ __forceinline__ void fma4(float4& a, float s, const float4& w) {
    a.x = fmaf(s, w.x, a.x);
    a.y = fmaf(s, w.y, a.y);
    a.z = fmaf(s, w.z, a.z);
    a.w = fmaf(s, w.w, a.w);
}

// Async global->LDS, 16B per lane. LDS dest = wave-uniform base + lane*16.
__device__ __forceinline__ void gload_lds16(const void* gsrc, void* ldst) {
    __builtin_amdgcn_global_load_lds(
        (const __attribute__((address_space(1))) void*)gsrc,
        (__attribute__((address_space(3))) void*)ldst, 16, 0, 0);
}

// Stage 800 float4 (32x100 tile) contiguously: 12 full 64-lane chunks + 32-lane tail.
__device__ __forceinline__ void stage800(const float4* __restrict__ src,
                                         float* dst, int t) {
    const int lane = t & 63, wid = t >> 6;
#pragma unroll
    for (int m = 0; m < 3; ++m) {
        const int chunk = wid * 3 + m;              // 0..11
        gload_lds16(src + chunk * 64 + lane, dst + chunk * 256);
    }
    if (wid == 3 && lane < 32)
        gload_lds16(src + 768 + lane, dst + 3072);  // tail f4 768..799
}

// Stage 500 float4 (20x100 tile): chunks 0..6 full + 52-lane tail chunk 7.
__device__ __forceinline__ void stage500(const float4* __restrict__ src,
                                         float* dst, int t) {
    const int lane = t & 63, wid = t >> 6;
#pragma unroll
    for (int m = 0; m < 2; ++m) {
        const int chunk = wid + 4 * m;              // 0..7
        if (chunk < 7 || lane < 52)
            gload_lds16(src + chunk * 64 + lane, dst + chunk * 256);
    }
}

// ---------------------------------------------------------------------------
// k1: LN + g = xn@Wxx + b, q/k GEMMs, masked aspect pooling (atomics).
// 512 blocks x 16 rows. Async (global_load_lds) double-buffered W staging,
// one barrier per K-tile.
// ---------------------------------------------------------------------------
__global__ __launch_bounds__(256, 3) void k1_fused(
    const float* __restrict__ x, const float* __restrict__ ln_a,
    const float* __restrict__ ln_b, const float* __restrict__ Wxx_w,
    const float* __restrict__ Wxx_b, const float* __restrict__ q_w,
    const float* __restrict__ q_b, const float* __restrict__ k_w,
    const float* __restrict__ k_b, const float* __restrict__ amask,
    float* __restrict__ g, float* __restrict__ qt, float* __restrict__ ktb,
    float* __restrict__ aspect_raw)
{
    __shared__ __align__(16) float s_w[2][3200];
    __shared__ float s_xn[2][16 * 36];
    __shared__ float s_gt[16 * 100];
    __shared__ float s_ln[1536];
    __shared__ float s_mean[16], s_rinv[16];

    const int t = threadIdx.x;
    const int r0 = blockIdx.x * 16;
    const int wid = t >> 6, lane = t & 63;

    if (t < 192) {
        ((float4*)s_ln)[t] = ((const float4*)ln_a)[t];
        ((float4*)(s_ln + 768))[t] = ((const float4*)ln_b)[t];
    }
    for (int rr = wid * 4; rr < wid * 4 + 4; ++rr) {
        const float* xr = x + (size_t)(r0 + rr) * CD;
        float xv[12];
        float s = 0.f;
#pragma unroll
        for (int m = 0; m < 12; ++m) { xv[m] = xr[lane + 64 * m]; s += xv[m]; }
#pragma unroll
        for (int o = 32; o; o >>= 1) s += __shfl_xor(s, o);
        float mean = s * (1.0f / 768.0f);
        float sq = 0.f;
#pragma unroll
        for (int m = 0; m < 12; ++m) { float d = xv[m] - mean; sq = fmaf(d, d, sq); }
#pragma unroll
        for (int o = 32; o; o >>= 1) sq += __shfl_xor(sq, o);
        if (lane == 0) {
            s_mean[rr] = mean;
            s_rinv[rr] = 1.0f / (sqrtf(sq * (1.0f / 767.0f)) + 1e-6f);
        }
    }

    const float4* wsrc = (const float4*)Wxx_w;
    stage800(wsrc, s_w[0], t);                 // async W tile0, hidden by stats
    const int rA = t >> 5, cA = t & 31;
    float xa = x[(size_t)(r0 + rA) * CD + cA];
    float xb = x[(size_t)(r0 + rA + 8) * CD + cA];

    __syncthreads();   // stats + s_ln visible; tile0 drained

    {
        float la = s_ln[cA], lbv = s_ln[768 + cA];
        s_xn[0][rA * 36 + cA] = fmaf(la, (xa - s_mean[rA]) * s_rinv[rA], lbv);
        s_xn[0][(rA + 8) * 36 + cA] = fmaf(la, (xb - s_mean[rA + 8]) * s_rinv[rA + 8], lbv);
    }
    __syncthreads();

    const int cg2 = t % 25, rg = t / 25;
    const int c = cg2 * 4;
    float4 acc0 = make_float4(0.f, 0.f, 0.f, 0.f);
    float4 acc1 = make_float4(0.f, 0.f, 0.f, 0.f);

    for (int kt = 0; kt < 24; ++kt) {
        if (kt < 23) {
            stage800(wsrc + (size_t)(kt + 1) * 800, s_w[(kt + 1) & 1], t);
            int gc = (kt + 1) * 32 + cA;
            xa = x[(size_t)(r0 + rA) * CD + gc];
            xb = x[(size_t)(r0 + rA + 8) * CD + gc];
        }
        if (t < 200) {
            const float* wb = s_w[kt & 1];
            const float* xbuf = s_xn[kt & 1];
#pragma unroll 2
            for (int kk = 0; kk < 32; kk += 4) {
                float4 a0 = *(const float4*)&xbuf[(rg * 2 + 0) * 36 + kk];
                float4 a1 = *(const float4*)&xbuf[(rg * 2 + 1) * 36 + kk];
                float4 v0 = *(const float4*)&wb[(kk + 0) * 100 + c];
                float4 v1 = *(const float4*)&wb[(kk + 1) * 100 + c];
                float4 v2 = *(const float4*)&wb[(kk + 2) * 100 + c];
                float4 v3 = *(const float4*)&wb[(kk + 3) * 100 + c];
                fma4(acc0, a0.x, v0); fma4(acc0, a0.y, v1); fma4(acc0, a0.z, v2); fma4(acc0, a0.w, v3);
                fma4(acc1, a1.x, v0); fma4(acc1, a1.y, v1); fma4(acc1, a1.z, v2); fma4(acc1, a1.w, v3);
            }
        }
        if (kt < 23) {
            int gc = (kt + 1) * 32 + cA;
            float la = s_ln[gc], lbv = s_ln[768 + gc];
            float* xd = s_xn[(kt + 1) & 1];
            xd[rA * 36 + cA] = fmaf(la, (xa - s_mean[rA]) * s_rinv[rA], lbv);
            xd[(rA + 8) * 36 + cA] = fmaf(la, (xb - s_mean[rA + 8]) * s_rinv[rA + 8], lbv);
        }
        __syncthreads();
    }

    if (t < 200) {
        float4 bias = *(const float4*)&Wxx_b[c];
        float4 rv0, rv1;
        rv0.x = acc0.x + bias.x; rv0.y = acc0.y + bias.y; rv0.z = acc0.z + bias.z; rv0.w = acc0.w + bias.w;
        rv1.x = acc1.x + bias.x; rv1.y = acc1.y + bias.y; rv1.z = acc1.z + bias.z; rv1.w = acc1.w + bias.w;
        float4 rv[2] = { rv0, rv1 };
#pragma unroll
        for (int q = 0; q < 2; ++q) {
            int row = r0 + rg * 2 + q;
            *(float4*)&g[(size_t)row * CATT + c] = rv[q];
            *(float4*)&s_gt[(rg * 2 + q) * 100 + c] = rv[q];
            float m = amask[row];
            if (m != 0.f) {
                int b = row >> 8;
                atomicAdd(&aspect_raw[b * CATT + c + 0], m * rv[q].x);
                atomicAdd(&aspect_raw[b * CATT + c + 1], m * rv[q].y);
                atomicAdd(&aspect_raw[b * CATT + c + 2], m * rv[q].z);
                atomicAdd(&aspect_raw[b * CATT + c + 3], m * rv[q].w);
            }
        }
    }

    // q/k GEMMs: 10 pipelined 20x100 async tiles (0-4 q_w, 5-9 k_w)
    const float4* qw4 = (const float4*)q_w;
    const float4* kw4 = (const float4*)k_w;
    stage500(qw4, s_w[0], t);
    __syncthreads();   // s_gt visible + tile0 drained

    float4 p0 = make_float4(0.f, 0.f, 0.f, 0.f);
    float4 p1 = make_float4(0.f, 0.f, 0.f, 0.f);
    for (int tau = 0; tau < 10; ++tau) {
        if (tau < 9) {
            const float4* src = (tau + 1 < 5) ? qw4 + (size_t)(tau + 1) * 500
                                              : kw4 + (size_t)(tau - 4) * 500;
            stage500(src, s_w[(tau + 1) & 1], t);
        }
        if (t < 200) {
            const float* wb = s_w[tau & 1];
            const int kb = (tau % 5) * 20;
#pragma unroll 2
            for (int kk = 0; kk < 20; kk += 4) {
                float4 a0 = *(const float4*)&s_gt[(rg * 2 + 0) * 100 + kb + kk];
                float4 a1 = *(const float4*)&s_gt[(rg * 2 + 1) * 100 + kb + kk];
                float4 v0 = *(const float4*)&wb[(kk + 0) * 100 + c];
                float4 v1 = *(const float4*)&wb[(kk + 1) * 100 + c];
                float4 v2 = *(const float4*)&wb[(kk + 2) * 100 + c];
                float4 v3 = *(const float4*)&wb[(kk + 3) * 100 + c];
                fma4(p0, a0.x, v0); fma4(p0, a0.y, v1); fma4(p0, a0.z, v2); fma4(p0, a0.w, v3);
                fma4(p1, a1.x, v0); fma4(p1, a1.y, v1); fma4(p1, a1.z, v2); fma4(p1, a1.w, v3);
            }
            if (tau == 4 || tau == 9) {
                const float* bb = (tau == 4) ? q_b : k_b;
                float* outp = (tau == 4) ? qt : ktb;
                float4 bias = *(const float4*)&bb[c];
                p0.x += bias.x; p0.y += bias.y; p0.z += bias.z; p0.w += bias.w;
                p1.x += bias.x; p1.y += bias.y; p1.z += bias.z; p1.w += bias.w;
                const int h = c / CDK, d = c % CDK;
                float4 rv[2] = { p0, p1 };
#pragma unroll
                for (int q = 0; q < 2; ++q) {
                    int row = r0 + rg * 2 + q;
                    int bidx = row >> 8, l = row & 255;
                    *(float4*)&outp[((size_t)(bidx * CH + h) * CL + l) * CDK + d] = rv[q];
                }
                p0 = make_float4(0.f, 0.f, 0.f, 0.f);
                p1 = make_float4(0.f, 0.f, 0.f, 0.f);
            }
        }
        __syncthreads();
    }
}

// ---------------------------------------------------------------------------
// k45: inline asp + softmax (adjS in LDS, adjW->global) + GCN0 + rank-1.
// GEMM staging via async global_load_lds; g tile0 hidden behind softmax.
// ---------------------------------------------------------------------------
__global__ __launch_bounds__(256, 3) void k45_attn_gcn0(
    const float* __restrict__ qt, const float* __restrict__ ktb,
    const float* __restrict__ aspect_raw, const float* __restrict__ amask,
    const float* __restrict__ dense_w, const float* __restrict__ dense_b,
    const float* __restrict__ bias_m, const int* __restrict__ src_mask,
    const float* __restrict__ shortm, const float* __restrict__ Wx_w,
    const float* __restrict__ g, const float* __restrict__ W_w,
    const float* __restrict__ W_b, float* __restrict__ adjW,
    float* __restrict__ go1, float* __restrict__ t1, float* __restrict__ t2,
    float* __restrict__ gW2S)
{
    constexpr int ICH = 16;
    __shared__ float s_pool[16 * 260];
    __shared__ __align__(16) float s_w[2][3200];
    __shared__ float s_q[CH * 320];
    __shared__ float s_red[CH][64];
    __shared__ float s_was[5];
    __shared__ float s_aspb[20];
    __shared__ float s_w1[100], s_w2[100];
    __shared__ float s_g1row[16];

    const int b = blockIdx.x >> 4, ic = blockIdx.x & 15;
    const int i0 = ic * ICH;
    const int t = threadIdx.x, lane = t & 63, wid = t >> 6;
    const int j = t;

    if (t < 5) {
        float s = 0.f;
        for (int k2 = 0; k2 < 5; ++k2) s += Wx_w[t * 5 + k2];
        s_was[t] = s;
    }
    if (t < 100) {
        float a = 0.f, c2 = 0.f;
#pragma unroll
        for (int h = 0; h < 5; ++h) {
            a += Wx_w[(5 + t) * 5 + h];
            c2 += Wx_w[(105 + t) * 5 + h];
        }
        s_w1[t] = a; s_w2[t] = c2;
    }
    float wn = 0.f;
    if (t < 64) {
        float4 mv = ((const float4*)amask)[b * 64 + t];
        wn = mv.x + mv.y + mv.z + mv.w;
#pragma unroll
        for (int o = 32; o; o >>= 1) wn += __shfl_xor(wn, o);
    }
    if (t < 20) {
        float a = 0.f;
        for (int d = 0; d < CATT; ++d)
            a = fmaf(aspect_raw[b * CATT + d], dense_w[d * CDK + t], a);
        s_aspb[t] = a / wn + dense_b[t];
    }
    {
        const float* qbase = qt + (size_t)b * CH * CL * CDK + (size_t)i0 * CDK;
        for (int i = t; i < CH * 320; i += 256) {
            int h = i / 320, r = i % 320;
            s_q[i] = qbase[(size_t)h * CL * CDK + r];
        }
    }

    const bool masked = (src_mask[b * CL + j] == 0);
    const float bm = bias_m[0];
    const float rs20 = 0.223606797749978969f;

    float smv[ICH];
#pragma unroll
    for (int ii = 0; ii < ICH; ++ii)
        smv[ii] = shortm[(size_t)(b * CL + i0 + ii) * CL + j];

    float accS[ICH], accW[ICH];
#pragma unroll
    for (int ii = 0; ii < ICH; ++ii) { accS[ii] = 0.f; accW[ii] = 0.f; }

    const float4* g4 = (const float4*)g + (size_t)b * 6400;
    stage800(g4, s_w[0], t);     // g tile0 flies behind the whole softmax
    __syncthreads();

    for (int h = 0; h < CH; ++h) {
        float4 kr[5];
        const float* kp = ktb + ((size_t)(b * CH + h) * CL + j) * CDK;
#pragma unroll
        for (int m = 0; m < 5; ++m) kr[m] = *(const float4*)(kp + 4 * m);
        const float was_h = s_was[h];
        float s = bm;
#pragma unroll
        for (int m = 0; m < 5; ++m) {
            s = fmaf(s_aspb[4 * m + 0], kr[m].x, s);
            s = fmaf(s_aspb[4 * m + 1], kr[m].y, s);
            s = fmaf(s_aspb[4 * m + 2], kr[m].z, s);
            s = fmaf(s_aspb[4 * m + 3], kr[m].w, s);
        }
        const float aspsc = tanhf(s);

        float pv[ICH];
#pragma unroll
        for (int ii = 0; ii < ICH; ++ii) {
            const float* qrow = &s_q[h * 320 + ii * CDK];
            float sc = 0.f;
#pragma unroll
            for (int m = 0; m < 5; ++m) {
                float4 q4 = *(const float4*)(qrow + 4 * m);
                sc = fmaf(q4.x, kr[m].x, sc);
                sc = fmaf(q4.y, kr[m].y, sc);
                sc = fmaf(q4.z, kr[m].z, sc);
                sc = fmaf(q4.w, kr[m].w, sc);
            }
            sc = fmaf(sc, rs20, aspsc) + smv[ii];
            float p = masked ? 0.f : __expf(sc);
            pv[ii] = p;
            float ssum = p;
#pragma unroll
            for (int o = 32; o; o >>= 1) ssum += __shfl_xor(ssum, o);
            if (lane == 0) s_red[h][ii * 4 + wid] = ssum;
        }
        __syncthreads();
#pragma unroll
        for (int ii = 0; ii < ICH; ++ii) {
            float tot = s_red[h][ii * 4 + 0] + s_red[h][ii * 4 + 1] +
                        s_red[h][ii * 4 + 2] + s_red[h][ii * 4 + 3];
            float pn = pv[ii] * __frcp_rn(tot);
            accS[ii] += pn;
            accW[ii] = fmaf(was_h, pn, accW[ii]);
        }
    }

#pragma unroll
    for (int ii = 0; ii < ICH; ++ii) {
        adjW[(size_t)(b * CL + i0 + ii) * CL + j] = accW[ii];
        s_pool[ii * 260 + j] = accS[ii];
    }
    __syncthreads();   // publish adjS tile (g tile0 long since drained)

    // GEMM1: Ax = adjS @ g, 8 async-pipelined 32x100 tiles
    const int cg2 = t % 25, rg = t / 25;
    const int c = cg2 * 4;
    float4 acc0 = make_float4(0.f, 0.f, 0.f, 0.f);
    float4 acc1 = make_float4(0.f, 0.f, 0.f, 0.f);
    for (int jt = 0; jt < 8; ++jt) {
        if (jt < 7)
            stage800(g4 + (size_t)(jt + 1) * 800, s_w[(jt + 1) & 1], t);
        if (t < 200) {
            const float* wb = s_w[jt & 1];
#pragma unroll 2
            for (int kk = 0; kk < 32; kk += 4) {
                float4 a0 = *(const float4*)&s_pool[(rg * 2 + 0) * 260 + jt * 32 + kk];
                float4 a1 = *(const float4*)&s_pool[(rg * 2 + 1) * 260 + jt * 32 + kk];
                float4 v0 = *(const float4*)&wb[(kk + 0) * 100 + c];
                float4 v1 = *(const float4*)&wb[(kk + 1) * 100 + c];
                float4 v2 = *(const float4*)&wb[(kk + 2) * 100 + c];
                float4 v3 = *(const float4*)&wb[(kk + 3) * 100 + c];
                fma4(acc0, a0.x, v0); fma4(acc0, a0.y, v1); fma4(acc0, a0.z, v2); fma4(acc0, a0.w, v3);
                fma4(acc1, a1.x, v0); fma4(acc1, a1.y, v1); fma4(acc1, a1.z, v2); fma4(acc1, a1.w, v3);
            }
        }
        __syncthreads();
    }

    float* s_ax = s_pool;
    if (t < 200) {
        float4 r;
        r.x = acc0.x * 0.2f; r.y = acc0.y * 0.2f; r.z = acc0.z * 0.2f; r.w = acc0.w * 0.2f;
        *(float4*)&s_ax[(rg * 2 + 0) * 108 + c] = r;
        r.x = acc1.x * 0.2f; r.y = acc1.y * 0.2f; r.z = acc1.z * 0.2f; r.w = acc1.w * 0.2f;
        *(float4*)&s_ax[(rg * 2 + 1) * 108 + c] = r;
    }
    const float4* ww4 = (const float4*)W_w;
    stage500(ww4, s_w[0], t);
    __syncthreads();

    // GEMM2: go1 = relu(Ax @ W_w + W_b), 5 async-pipelined 20x100 tiles
    float4 o0 = make_float4(0.f, 0.f, 0.f, 0.f);
    float4 o1 = make_float4(0.f, 0.f, 0.f, 0.f);
    for (int wt = 0; wt < 5; ++wt) {
        if (wt < 4)
            stage500(ww4 + (size_t)(wt + 1) * 500, s_w[(wt + 1) & 1], t);
        if (t < 200) {
            const float* wb = s_w[wt & 1];
            const int kb = wt * 20;
#pragma unroll 2
            for (int kk = 0; kk < 20; kk += 4) {
                float4 a0 = *(const float4*)&s_ax[(rg * 2 + 0) * 108 + kb + kk];
                float4 a1 = *(const float4*)&s_ax[(rg * 2 + 1) * 108 + kb + kk];
                float4 v0 = *(const float4*)&wb[(kk + 0) * 100 + c];
                float4 v1 = *(const float4*)&wb[(kk + 1) * 100 + c];
                float4 v2 = *(const float4*)&wb[(kk + 2) * 100 + c];
                float4 v3 = *(const float4*)&wb[(kk + 3) * 100 + c];
                fma4(o0, a0.x, v0); fma4(o0, a0.y, v1); fma4(o0, a0.z, v2); fma4(o0, a0.w, v3);
                fma4(o1, a1.x, v0); fma4(o1, a1.y, v1); fma4(o1, a1.z, v2); fma4(o1, a1.w, v3);
            }
        }
        __syncthreads();
    }

    float* s_go = s_pool + 1728;
    if (t < 200) {
        float4 bias = *(const float4*)&W_b[c];
        o0.x = fmaxf(o0.x + bias.x, 0.f); o0.y = fmaxf(o0.y + bias.y, 0.f);
        o0.z = fmaxf(o0.z + bias.z, 0.f); o0.w = fmaxf(o0.w + bias.w, 0.f);
        o1.x = fmaxf(o1.x + bias.x, 0.f); o1.y = fmaxf(o1.y + bias.y, 0.f);
        o1.z = fmaxf(o1.z + bias.z, 0.f); o1.w = fmaxf(o1.w + bias.w, 0.f);
        *(float4*)&go1[(size_t)(b * CL + i0 + rg * 2 + 0) * CATT + c] = o0;
        *(float4*)&go1[(size_t)(b * CL + i0 + rg * 2 + 1) * CATT + c] = o1;
        *(float4*)&s_go[(rg * 2 + 0) * 104 + c] = o0;
        *(float4*)&s_go[(rg * 2 + 1) * 104 + c] = o1;
    }
    __syncthreads();

    if (t < 128) {
        int r = t >> 3, seg = t & 7;
        int e0 = seg * 13, e1 = e0 + 13 < 100 ? e0 + 13 : 100;
        float a = 0.f, c2 = 0.f;
        for (int e = e0; e < e1; ++e) {
            float v = s_go[r * 104 + e];
            a = fmaf(v, s_w1[e], a);
            c2 = fmaf(v, s_w2[e], c2);
        }
        a += __shfl_xor(a, 1); a += __shfl_xor(a, 2); a += __shfl_xor(a, 4);
        c2 += __shfl_xor(c2, 1); c2 += __shfl_xor(c2, 2); c2 += __shfl_xor(c2, 4);
        if (seg == 0) {
            s_g1row[r] = a;
            gW2S[b * CL + i0 + r] = c2;
        }
    }
    __syncthreads();

    if (t < 100) {
        float a = 0.f, s2 = 0.f;
#pragma unroll
        for (int r = 0; r < 16; ++r) {
            float v = s_go[r * 104 + t];
            a = fmaf(s_g1row[r], v, a);
            s2 += v;
        }
        atomicAdd(&t1[b * CATT + t], a);
        atomicAdd(&t2[b * CATT + t], s2);
    }
}

// ---------------------------------------------------------------------------
// k7: GCN1 + rank-1 corrections + masked pooling -> out1_raw atomics;
// last block per batch runs the classifier (k8 folded in).
// ---------------------------------------------------------------------------
__global__ __launch_bounds__(256, 3) void k7_gcn1(
    const float* __restrict__ adjW, const float* __restrict__ go1,
    const float* __restrict__ W_w, const float* __restrict__ W_b,
    const float* __restrict__ t1, const float* __restrict__ t2,
    const float* __restrict__ gW2S, const float* __restrict__ Wx_b,
    const float* __restrict__ amask, float* __restrict__ out1_raw,
    int* __restrict__ cnt, const float* __restrict__ clf_w,
    const float* __restrict__ clf_b, float* __restrict__ out)
{
    __shared__ float s_pool[16 * 260];
    __shared__ __align__(16) float s_w[2][3200];
    __shared__ int s_islast;
    const int b = blockIdx.x >> 4, ic = blockIdx.x & 15;
    const int i0 = ic * 16;
    const int t = threadIdx.x;

    const float4* g4 = (const float4*)go1 + (size_t)b * 6400;
    stage800(g4, s_w[0], t);   // async go1 tile0, hidden by adjW staging
    {
        const float4* asrc = (const float4*)adjW + (size_t)(b * CL + i0) * 64;
#pragma unroll
        for (int m = 0; m < 4; ++m) {
            int i = t + 256 * m;
            int row = i >> 6, c4 = i & 63;
            *(float4*)&s_pool[row * 260 + c4 * 4] = asrc[i];
        }
    }
    __syncthreads();

    const int cg2 = t % 25, rg = t / 25;
    const int c = cg2 * 4;
    float4 acc0 = make_float4(0.f, 0.f, 0.f, 0.f);
    float4 acc1 = make_float4(0.f, 0.f, 0.f, 0.f);
    for (int jt = 0; jt < 8; ++jt) {
        if (jt < 7)
            stage800(g4 + (size_t)(jt + 1) * 800, s_w[(jt + 1) & 1], t);
        if (t < 200) {
            const float* wb = s_w[jt & 1];
#pragma unroll 2
            for (int kk = 0; kk < 32; kk += 4) {
                float4 a0 = *(const float4*)&s_pool[(rg * 2 + 0) * 260 + jt * 32 + kk];
                float4 a1 = *(const float4*)&s_pool[(rg * 2 + 1) * 260 + jt * 32 + kk];
                float4 v0 = *(const float4*)&wb[(kk + 0) * 100 + c];
                float4 v1 = *(const float4*)&wb[(kk + 1) * 100 + c];
                float4 v2 = *(const float4*)&wb[(kk + 2) * 100 + c];
                float4 v3 = *(const float4*)&wb[(kk + 3) * 100 + c];
                fma4(acc0, a0.x, v0); fma4(acc0, a0.y, v1); fma4(acc0, a0.z, v2); fma4(acc0, a0.w, v3);
                fma4(acc1, a1.x, v0); fma4(acc1, a1.y, v1); fma4(acc1, a1.z, v2); fma4(acc1, a1.w, v3);
            }
        }
        __syncthreads();
    }

    float* s_ax = s_pool;
    if (t < 200) {
        float wxbs = Wx_b[0] + Wx_b[1] + Wx_b[2] + Wx_b[3] + Wx_b[4];
        float4 t1v = *(const float4*)&t1[b * CATT + c];
        float4 t2v = *(const float4*)&t2[b * CATT + c];
        float gw0 = gW2S[b * CL + i0 + rg * 2 + 0] + wxbs;
        float gw1 = gW2S[b * CL + i0 + rg * 2 + 1] + wxbs;
        float4 r;
        r.x = (acc0.x + t1v.x + gw0 * t2v.x) * 0.2f;
        r.y = (acc0.y + t1v.y + gw0 * t2v.y) * 0.2f;
        r.z = (acc0.z + t1v.z + gw0 * t2v.z) * 0.2f;
        r.w = (acc0.w + t1v.w + gw0 * t2v.w) * 0.2f;
        *(float4*)&s_ax[(rg * 2 + 0) * 108 + c] = r;
        r.x = (acc1.x + t1v.x + gw1 * t2v.x) * 0.2f;
        r.y = (acc1.y + t1v.y + gw1 * t2v.y) * 0.2f;
        r.z = (acc1.z + t1v.z + gw1 * t2v.z) * 0.2f;
        r.w = (acc1.w + t1v.w + gw1 * t2v.w) * 0.2f;
        *(float4*)&s_ax[(rg * 2 + 1) * 108 + c] = r;
    }
    const float4* ww4 = (const float4*)W_w;
    stage500(ww4, s_w[0], t);
    __syncthreads();

    float4 o0 = make_float4(0.f, 0.f, 0.f, 0.f);
    float4 o1 = make_float4(0.f, 0.f, 0.f, 0.f);
    for (int wt = 0; wt < 5; ++wt) {
        if (wt < 4)
            stage500(ww4 + (size_t)(wt + 1) * 500, s_w[(wt + 1) & 1], t);
        if (t < 200) {
            const float* wb = s_w[wt & 1];
            const int kb = wt * 20;
#pragma unroll 2
            for (int kk = 0; kk < 20; kk += 4) {
                float4 a0 = *(const float4*)&s_ax[(rg * 2 + 0) * 108 + kb + kk];
                float4 a1 = *(const float4*)&s_ax[(rg * 2 + 1) * 108 + kb + kk];
                float4 v0 = *(const float4*)&wb[(kk + 0) * 100 + c];
                float4 v1 = *(const float4*)&wb[(kk + 1) * 100 + c];
                float4 v2 = *(const float4*)&wb[(kk + 2) * 100 + c];
                float4 v3 = *(const float4*)&wb[(kk + 3) * 100 + c];
                fma4(o0, a0.x, v0); fma4(o0, a0.y, v1); fma4(o0, a0.z, v2); fma4(o0, a0.w, v3);
                fma4(o1, a1.x, v0); fma4(o1, a1.y, v1); fma4(o1, a1.z, v2); fma4(o1, a1.w, v3);
            }
        }
        __syncthreads();
    }

    if (t < 200) {
        float4 bias = *(const float4*)&W_b[c];
        o0.x = fmaxf(o0.x + bias.x, 0.f); o0.y = fmaxf(o0.y + bias.y, 0.f);
        o0.z = fmaxf(o0.z + bias.z, 0.f); o0.w = fmaxf(o0.w + bias.w, 0.f);
        o1.x = fmaxf(o1.x + bias.x, 0.f); o1.y = fmaxf(o1.y + bias.y, 0.f);
        o1.z = fmaxf(o1.z + bias.z, 0.f); o1.w = fmaxf(o1.w + bias.w, 0.f);
        float4 ov[2] = { o0, o1 };
#pragma unroll
        for (int q = 0; q < 2; ++q) {
            int row = b * CL + i0 + rg * 2 + q;
            float m = amask[row];
            if (m != 0.f) {
                atomicAdd(&out1_raw[b * CATT + c + 0], m * ov[q].x);
                atomicAdd(&out1_raw[b * CATT + c + 1], m * ov[q].y);
                atomicAdd(&out1_raw[b * CATT + c + 2], m * ov[q].z);
                atomicAdd(&out1_raw[b * CATT + c + 3], m * ov[q].w);
            }
        }
    }

    // ---- last block of this batch runs the classifier (k8 folded in)
    __syncthreads();
    if (t == 0) {
        __threadfence();
        int prev = atomicAdd(&cnt[b], 1);
        s_islast = (prev == 15) ? 1 : 0;
    }
    __syncthreads();
    if (s_islast) {
        __threadfence();
        float wn = 0.f;
        if (t < 64) {
            float4 mv = ((const float4*)amask)[b * 64 + t];
            wn = mv.x + mv.y + mv.z + mv.w;
#pragma unroll
            for (int o = 32; o; o >>= 1) wn += __shfl_xor(wn, o);
        }
        if (t < 3) {
            float rwn = 1.f / wn;
            float a = clf_b[t];
            for (int d = 0; d < CATT; ++d) {
                float v = __hip_atomic_load(&out1_raw[b * CATT + d],
                                            __ATOMIC_RELAXED, __HIP_MEMORY_SCOPE_AGENT);
                a = fmaf(v * rwn, clf_w[d * 3 + t], a);
            }
            out[b * 3 + t] = a;
        }
    }
}

// ---------------------------------------------------------------------------
extern "C" void kernel_launch(void* const* d_in, const int* in_sizes, int n_in,
                              void* d_out, int out_size, void* d_ws, size_t ws_size,
                              hipStream_t stream) {
    const float* seq     = (const float*)d_in[0];
    const int*   srcm    = (const int*)d_in[1];
    const float* amask   = (const float*)d_in[2];
    const float* shortm  = (const float*)d_in[3];
    const float* ln_a    = (const float*)d_in[4];
    const float* ln_b    = (const float*)d_in[5];
    const float* Wxx_w   = (const float*)d_in[6];
    const float* Wxx_b   = (const float*)d_in[7];
    const float* q_w     = (const float*)d_in[8];
    const float* q_b     = (const float*)d_in[9];
    const float* k_w     = (const float*)d_in[10];
    const float* k_b     = (const float*)d_in[11];
    const float* dense_w = (const float*)d_in[12];
    const float* dense_b = (const float*)d_in[13];
    const float* bias_m  = (const float*)d_in[14];
    const float* W_w     = (const float*)d_in[15];
    const float* W_b     = (const float*)d_in[16];
    const float* Wx_w    = (const float*)d_in[17];
    const float* Wx_b    = (const float*)d_in[18];
    const float* clf_w   = (const float*)d_in[19];
    const float* clf_b   = (const float*)d_in[20];
    float* out = (float*)d_out;

    float* ws         = (float*)d_ws;
    float* g          = ws;
    float* qt         = g + 819200;
    float* ktb        = qt + 819200;
    float* go1        = ktb + 819200;
    float* adjW       = go1 + 819200;
    float* aspect_raw = adjW + 2097152;
    float* t1         = aspect_raw + 3200;
    float* t2         = t1 + 3200;
    float* out1_raw   = t2 + 3200;
    int*   cnt        = (int*)(out1_raw + 3200);   // 32 ints
    float* gW2S       = (float*)(cnt + 32);        // 8192

    // zero aspect_raw, t1, t2, out1_raw (4*3200 floats) + cnt (32 ints)
    hipMemsetAsync(aspect_raw, 0, (4 * 3200 + 32) * sizeof(float), stream);

    hipLaunchKernelGGL(k1_fused, dim3(512), dim3(256), 0, stream, seq, ln_a, ln_b,
                       Wxx_w, Wxx_b, q_w, q_b, k_w, k_b, amask, g, qt, ktb, aspect_raw);
    hipLaunchKernelGGL(k45_attn_gcn0, dim3(512), dim3(256), 0, stream,
                       qt, ktb, aspect_raw, amask, dense_w, dense_b, bias_m, srcm,
                       shortm, Wx_w, g, W_w, W_b, adjW, go1, t1, t2, gW2S);
    hipLaunchKernelGGL(k7_gcn1, dim3(512), dim3(256), 0, stream,
                       adjW, go1, W_w, W_b, t1, t2, gW2S, Wx_b, amask, out1_raw,
                       cnt, clf_w, clf_b, out);
}

// Round 10
// 251.118 us; speedup vs baseline: 1.3544x; 1.0260x over previous
//
#include <hip/hip_runtime.h>
#include <math.h>

constexpr int CL = 256;
constexpr int CD = 768;
constexpr int CATT = 100;
constexpr int CH = 5;
constexpr int CDK = 20;

__device__ __forceinline__ void fma4(float4& a, float s, const float4& w) {
    a.x = fmaf(s, w.x, a.x);
    a.y = fmaf(s, w.y, a.y);
    a.z = fmaf(s, w.z, a.z);
    a.w = fmaf(s, w.w, a.w);
}

// ---------------------------------------------------------------------------
// k1: LN + g = xn@Wxx + b, q/k GEMMs. 512 blocks x 16 rows, register-staged
// double-buffered tiles (r5 structure, best measured). No atomics.
// ---------------------------------------------------------------------------
__global__ __launch_bounds__(256, 3) void k1_fused(
    const float* __restrict__ x, const float* __restrict__ ln_a,
    const float* __restrict__ ln_b, const float* __restrict__ Wxx_w,
    const float* __restrict__ Wxx_b, const float* __restrict__ q_w,
    const float* __restrict__ q_b, const float* __restrict__ k_w,
    const float* __restrict__ k_b, float* __restrict__ g,
    float* __restrict__ qt, float* __restrict__ ktb)
{
    __shared__ float s_w[2][3200];
    __shared__ float s_xn[2][16 * 36];
    __shared__ float s_gt[16 * 100];
    __shared__ float s_ln[1536];
    __shared__ float s_mean[16], s_rinv[16];

    const int t = threadIdx.x;
    const int r0 = blockIdx.x * 16;
    const int wid = t >> 6, lane = t & 63;

    if (t < 192) {
        ((float4*)s_ln)[t] = ((const float4*)ln_a)[t];
        ((float4*)(s_ln + 768))[t] = ((const float4*)ln_b)[t];
    }
    for (int rr = wid * 4; rr < wid * 4 + 4; ++rr) {
        const float* xr = x + (size_t)(r0 + rr) * CD;
        float xv[12];
        float s = 0.f;
#pragma unroll
        for (int m = 0; m < 12; ++m) { xv[m] = xr[lane + 64 * m]; s += xv[m]; }
#pragma unroll
        for (int o = 32; o; o >>= 1) s += __shfl_xor(s, o);
        float mean = s * (1.0f / 768.0f);
        float sq = 0.f;
#pragma unroll
        for (int m = 0; m < 12; ++m) { float d = xv[m] - mean; sq = fmaf(d, d, sq); }
#pragma unroll
        for (int o = 32; o; o >>= 1) sq += __shfl_xor(sq, o);
        if (lane == 0) {
            s_mean[rr] = mean;
            s_rinv[rr] = 1.0f / (sqrtf(sq * (1.0f / 767.0f)) + 1e-6f);
        }
    }

    const float4* wsrc = (const float4*)Wxx_w;
    float4 w0 = wsrc[t], w1 = wsrc[t + 256], w2 = wsrc[t + 512], w3;
    if (t < 32) w3 = wsrc[t + 768];
    const int rA = t >> 5, cA = t & 31;
    float xa = x[(size_t)(r0 + rA) * CD + cA];
    float xb = x[(size_t)(r0 + rA + 8) * CD + cA];

    __syncthreads();

    {
        float4* d4 = (float4*)s_w[0];
        d4[t] = w0; d4[t + 256] = w1; d4[t + 512] = w2;
        if (t < 32) d4[t + 768] = w3;
        float la = s_ln[cA], lbv = s_ln[768 + cA];
        s_xn[0][rA * 36 + cA] = fmaf(la, (xa - s_mean[rA]) * s_rinv[rA], lbv);
        s_xn[0][(rA + 8) * 36 + cA] = fmaf(la, (xb - s_mean[rA + 8]) * s_rinv[rA + 8], lbv);
    }
    __syncthreads();

    const int cg2 = t % 25, rg = t / 25;
    const int c = cg2 * 4;
    float4 acc0 = make_float4(0.f, 0.f, 0.f, 0.f);
    float4 acc1 = make_float4(0.f, 0.f, 0.f, 0.f);

    for (int kt = 0; kt < 24; ++kt) {
        if (kt < 23) {
            const float4* ws = wsrc + (size_t)(kt + 1) * 800;
            w0 = ws[t]; w1 = ws[t + 256]; w2 = ws[t + 512];
            if (t < 32) w3 = ws[t + 768];
            int gc = (kt + 1) * 32 + cA;
            xa = x[(size_t)(r0 + rA) * CD + gc];
            xb = x[(size_t)(r0 + rA + 8) * CD + gc];
        }
        if (t < 200) {
            const float* wb = s_w[kt & 1];
            const float* xbuf = s_xn[kt & 1];
#pragma unroll 2
            for (int kk = 0; kk < 32; kk += 4) {
                float4 a0 = *(const float4*)&xbuf[(rg * 2 + 0) * 36 + kk];
                float4 a1 = *(const float4*)&xbuf[(rg * 2 + 1) * 36 + kk];
                float4 v0 = *(const float4*)&wb[(kk + 0) * 100 + c];
                float4 v1 = *(const float4*)&wb[(kk + 1) * 100 + c];
                float4 v2 = *(const float4*)&wb[(kk + 2) * 100 + c];
                float4 v3 = *(const float4*)&wb[(kk + 3) * 100 + c];
                fma4(acc0, a0.x, v0); fma4(acc0, a0.y, v1); fma4(acc0, a0.z, v2); fma4(acc0, a0.w, v3);
                fma4(acc1, a1.x, v0); fma4(acc1, a1.y, v1); fma4(acc1, a1.z, v2); fma4(acc1, a1.w, v3);
            }
        }
        if (kt < 23) {
            float4* d4 = (float4*)s_w[(kt + 1) & 1];
            d4[t] = w0; d4[t + 256] = w1; d4[t + 512] = w2;
            if (t < 32) d4[t + 768] = w3;
            int gc = (kt + 1) * 32 + cA;
            float la = s_ln[gc], lbv = s_ln[768 + gc];
            float* xd = s_xn[(kt + 1) & 1];
            xd[rA * 36 + cA] = fmaf(la, (xa - s_mean[rA]) * s_rinv[rA], lbv);
            xd[(rA + 8) * 36 + cA] = fmaf(la, (xb - s_mean[rA + 8]) * s_rinv[rA + 8], lbv);
        }
        __syncthreads();
    }

    if (t < 200) {
        float4 bias = *(const float4*)&Wxx_b[c];
        float4 rv0, rv1;
        rv0.x = acc0.x + bias.x; rv0.y = acc0.y + bias.y; rv0.z = acc0.z + bias.z; rv0.w = acc0.w + bias.w;
        rv1.x = acc1.x + bias.x; rv1.y = acc1.y + bias.y; rv1.z = acc1.z + bias.z; rv1.w = acc1.w + bias.w;
        float4 rv[2] = { rv0, rv1 };
#pragma unroll
        for (int q = 0; q < 2; ++q) {
            int row = r0 + rg * 2 + q;
            *(float4*)&g[(size_t)row * CATT + c] = rv[q];
            *(float4*)&s_gt[(rg * 2 + q) * 100 + c] = rv[q];
        }
    }

    // q/k GEMMs: 10 pipelined 20x100 tiles (0-4 q_w, 5-9 k_w)
    const float4* qw4 = (const float4*)q_w;
    const float4* kw4 = (const float4*)k_w;
    float4 sA = qw4[t], sB;
    if (t < 244) sB = qw4[t + 256];
    __syncthreads();
    {
        float4* d4 = (float4*)s_w[0];
        d4[t] = sA; if (t < 244) d4[t + 256] = sB;
    }
    __syncthreads();

    float4 p0 = make_float4(0.f, 0.f, 0.f, 0.f);
    float4 p1 = make_float4(0.f, 0.f, 0.f, 0.f);
    for (int tau = 0; tau < 10; ++tau) {
        if (tau < 9) {
            const float4* src = (tau + 1 < 5) ? qw4 + (size_t)(tau + 1) * 500
                                              : kw4 + (size_t)(tau - 4) * 500;
            sA = src[t]; if (t < 244) sB = src[t + 256];
        }
        if (t < 200) {
            const float* wb = s_w[tau & 1];
            const int kb = (tau % 5) * 20;
#pragma unroll 2
            for (int kk = 0; kk < 20; kk += 4) {
                float4 a0 = *(const float4*)&s_gt[(rg * 2 + 0) * 100 + kb + kk];
                float4 a1 = *(const float4*)&s_gt[(rg * 2 + 1) * 100 + kb + kk];
                float4 v0 = *(const float4*)&wb[(kk + 0) * 100 + c];
                float4 v1 = *(const float4*)&wb[(kk + 1) * 100 + c];
                float4 v2 = *(const float4*)&wb[(kk + 2) * 100 + c];
                float4 v3 = *(const float4*)&wb[(kk + 3) * 100 + c];
                fma4(p0, a0.x, v0); fma4(p0, a0.y, v1); fma4(p0, a0.z, v2); fma4(p0, a0.w, v3);
                fma4(p1, a1.x, v0); fma4(p1, a1.y, v1); fma4(p1, a1.z, v2); fma4(p1, a1.w, v3);
            }
            if (tau == 4 || tau == 9) {
                const float* bb = (tau == 4) ? q_b : k_b;
                float* outp = (tau == 4) ? qt : ktb;
                float4 bias = *(const float4*)&bb[c];
                p0.x += bias.x; p0.y += bias.y; p0.z += bias.z; p0.w += bias.w;
                p1.x += bias.x; p1.y += bias.y; p1.z += bias.z; p1.w += bias.w;
                const int h = c / CDK, d = c % CDK;
                float4 rv[2] = { p0, p1 };
#pragma unroll
                for (int q = 0; q < 2; ++q) {
                    int row = r0 + rg * 2 + q;
                    int bidx = row >> 8, l = row & 255;
                    *(float4*)&outp[((size_t)(bidx * CH + h) * CL + l) * CDK + d] = rv[q];
                }
                p0 = make_float4(0.f, 0.f, 0.f, 0.f);
                p1 = make_float4(0.f, 0.f, 0.f, 0.f);
            }
        }
        if (tau < 9) {
            float4* d4 = (float4*)s_w[(tau + 1) & 1];
            d4[t] = sA; if (t < 244) d4[t + 256] = sB;
        }
        __syncthreads();
    }
}

// ---------------------------------------------------------------------------
// k45: aspect (from g, masked) + softmax (adjS in LDS, adjW->global) + GCN0
// + rank-1 partials (deterministic stores -- no atomics, no zero-init).
// ---------------------------------------------------------------------------
__global__ __launch_bounds__(256, 3) void k45_attn_gcn0(
    const float* __restrict__ qt, const float* __restrict__ ktb,
    const float* __restrict__ amask, const float* __restrict__ dense_w,
    const float* __restrict__ dense_b, const float* __restrict__ bias_m,
    const int* __restrict__ src_mask, const float* __restrict__ shortm,
    const float* __restrict__ Wx_w, const float* __restrict__ g,
    const float* __restrict__ W_w, const float* __restrict__ W_b,
    float* __restrict__ adjW, float* __restrict__ go1,
    float* __restrict__ t12_part, float* __restrict__ gW2S)
{
    constexpr int ICH = 16;
    __shared__ float s_pool[16 * 260];
    __shared__ float s_w[2][3200];
    __shared__ float s_q[CH * 320];
    __shared__ float s_red[CH][64];
    __shared__ float s_was[5];
    __shared__ float s_aspb[20];
    __shared__ float s_asp[100];
    __shared__ float s_m[256];
    __shared__ float s_w1[100], s_w2[100];
    __shared__ float s_g1row[16];

    const int b = blockIdx.x >> 4, ic = blockIdx.x & 15;
    const int i0 = ic * ICH;
    const int t = threadIdx.x, lane = t & 63, wid = t >> 6;
    const int j = t;

    if (t < 5) {
        float s = 0.f;
        for (int k2 = 0; k2 < 5; ++k2) s += Wx_w[t * 5 + k2];
        s_was[t] = s;
    }
    if (t < 100) {
        float a = 0.f, c2 = 0.f;
#pragma unroll
        for (int h = 0; h < 5; ++h) {
            a += Wx_w[(5 + t) * 5 + h];
            c2 += Wx_w[(105 + t) * 5 + h];
        }
        s_w1[t] = a; s_w2[t] = c2;
    }
    float wn = 0.f;
    if (t < 64) {
        float4 mv = ((const float4*)amask)[b * 64 + t];
        *(float4*)&s_m[t * 4] = mv;
        wn = mv.x + mv.y + mv.z + mv.w;
#pragma unroll
        for (int o = 32; o; o >>= 1) wn += __shfl_xor(wn, o);
    }
    {
        const float* qbase = qt + (size_t)b * CH * CL * CDK + (size_t)i0 * CDK;
        for (int i = t; i < CH * 320; i += 256) {
            int h = i / 320, r = i % 320;
            s_q[i] = qbase[(size_t)h * CL * CDK + r];
        }
    }
    float smv[ICH];
#pragma unroll
    for (int ii = 0; ii < ICH; ++ii)
        smv[ii] = shortm[(size_t)(b * CL + i0 + ii) * CL + j];
    __syncthreads();

    if (t < 100) {   // masked aspect pooling from g (mask ~4 nonzero rows)
        float a = 0.f;
        for (int l = 0; l < CL; ++l) {
            float m = s_m[l];
            if (m != 0.f) a = fmaf(m, g[(size_t)(b * CL + l) * CATT + t], a);
        }
        s_asp[t] = a;
    }
    __syncthreads();
    if (t < 20) {    // wn is valid in wave 0 registers (t<64)
        float a = 0.f;
        for (int d = 0; d < CATT; ++d)
            a = fmaf(s_asp[d], dense_w[d * CDK + t], a);
        s_aspb[t] = a / wn + dense_b[t];
    }
    __syncthreads();

    const bool masked = (src_mask[b * CL + j] == 0);
    const float bm = bias_m[0];
    const float rs20 = 0.223606797749978969f;

    float accS[ICH], accW[ICH];
#pragma unroll
    for (int ii = 0; ii < ICH; ++ii) { accS[ii] = 0.f; accW[ii] = 0.f; }

    for (int h = 0; h < CH; ++h) {
        float4 kr[5];
        const float* kp = ktb + ((size_t)(b * CH + h) * CL + j) * CDK;
#pragma unroll
        for (int m = 0; m < 5; ++m) kr[m] = *(const float4*)(kp + 4 * m);
        const float was_h = s_was[h];
        float s = bm;
#pragma unroll
        for (int m = 0; m < 5; ++m) {
            s = fmaf(s_aspb[4 * m + 0], kr[m].x, s);
            s = fmaf(s_aspb[4 * m + 1], kr[m].y, s);
            s = fmaf(s_aspb[4 * m + 2], kr[m].z, s);
            s = fmaf(s_aspb[4 * m + 3], kr[m].w, s);
        }
        const float aspsc = tanhf(s);

        float pv[ICH];
#pragma unroll
        for (int ii = 0; ii < ICH; ++ii) {
            const float* qrow = &s_q[h * 320 + ii * CDK];
            float sc = 0.f;
#pragma unroll
            for (int m = 0; m < 5; ++m) {
                float4 q4 = *(const float4*)(qrow + 4 * m);
                sc = fmaf(q4.x, kr[m].x, sc);
                sc = fmaf(q4.y, kr[m].y, sc);
                sc = fmaf(q4.z, kr[m].z, sc);
                sc = fmaf(q4.w, kr[m].w, sc);
            }
            sc = fmaf(sc, rs20, aspsc) + smv[ii];
            float p = masked ? 0.f : __expf(sc);
            pv[ii] = p;
            float ssum = p;
#pragma unroll
            for (int o = 32; o; o >>= 1) ssum += __shfl_xor(ssum, o);
            if (lane == 0) s_red[h][ii * 4 + wid] = ssum;
        }
        __syncthreads();
#pragma unroll
        for (int ii = 0; ii < ICH; ++ii) {
            float tot = s_red[h][ii * 4 + 0] + s_red[h][ii * 4 + 1] +
                        s_red[h][ii * 4 + 2] + s_red[h][ii * 4 + 3];
            float pn = pv[ii] * __frcp_rn(tot);
            accS[ii] += pn;
            accW[ii] = fmaf(was_h, pn, accW[ii]);
        }
    }

#pragma unroll
    for (int ii = 0; ii < ICH; ++ii) {
        adjW[(size_t)(b * CL + i0 + ii) * CL + j] = accW[ii];
        s_pool[ii * 260 + j] = accS[ii];
    }

    // GEMM1: Ax = adjS @ g (8 pipelined 32x100 tiles)
    const int cg2 = t % 25, rg = t / 25;
    const int c = cg2 * 4;
    const float4* g4 = (const float4*)g + (size_t)b * 6400;
    float4 sA = g4[t], sB = g4[t + 256], sC = g4[t + 512], sD;
    if (t < 32) sD = g4[t + 768];
    {
        float4* d4 = (float4*)s_w[0];
        d4[t] = sA; d4[t + 256] = sB; d4[t + 512] = sC;
        if (t < 32) d4[t + 768] = sD;
    }
    __syncthreads();

    float4 acc0 = make_float4(0.f, 0.f, 0.f, 0.f);
    float4 acc1 = make_float4(0.f, 0.f, 0.f, 0.f);
    for (int jt = 0; jt < 8; ++jt) {
        if (jt < 7) {
            const float4* src = g4 + (size_t)(jt + 1) * 800;
            sA = src[t]; sB = src[t + 256]; sC = src[t + 512];
            if (t < 32) sD = src[t + 768];
        }
        if (t < 200) {
            const float* wb = s_w[jt & 1];
#pragma unroll 2
            for (int kk = 0; kk < 32; kk += 4) {
                float4 a0 = *(const float4*)&s_pool[(rg * 2 + 0) * 260 + jt * 32 + kk];
                float4 a1 = *(const float4*)&s_pool[(rg * 2 + 1) * 260 + jt * 32 + kk];
                float4 v0 = *(const float4*)&wb[(kk + 0) * 100 + c];
                float4 v1 = *(const float4*)&wb[(kk + 1) * 100 + c];
                float4 v2 = *(const float4*)&wb[(kk + 2) * 100 + c];
                float4 v3 = *(const float4*)&wb[(kk + 3) * 100 + c];
                fma4(acc0, a0.x, v0); fma4(acc0, a0.y, v1); fma4(acc0, a0.z, v2); fma4(acc0, a0.w, v3);
                fma4(acc1, a1.x, v0); fma4(acc1, a1.y, v1); fma4(acc1, a1.z, v2); fma4(acc1, a1.w, v3);
            }
        }
        if (jt < 7) {
            float4* d4 = (float4*)s_w[(jt + 1) & 1];
            d4[t] = sA; d4[t + 256] = sB; d4[t + 512] = sC;
            if (t < 32) d4[t + 768] = sD;
        }
        __syncthreads();
    }

    float* s_ax = s_pool;
    if (t < 200) {
        float4 r;
        r.x = acc0.x * 0.2f; r.y = acc0.y * 0.2f; r.z = acc0.z * 0.2f; r.w = acc0.w * 0.2f;
        *(float4*)&s_ax[(rg * 2 + 0) * 108 + c] = r;
        r.x = acc1.x * 0.2f; r.y = acc1.y * 0.2f; r.z = acc1.z * 0.2f; r.w = acc1.w * 0.2f;
        *(float4*)&s_ax[(rg * 2 + 1) * 108 + c] = r;
    }
    const float4* ww4 = (const float4*)W_w;
    sA = ww4[t]; if (t < 244) sB = ww4[t + 256];
    {
        float4* d4 = (float4*)s_w[0];
        d4[t] = sA; if (t < 244) d4[t + 256] = sB;
    }
    __syncthreads();

    // GEMM2: go1 = relu(Ax @ W_w + W_b), 5 pipelined 20x100 tiles
    float4 o0 = make_float4(0.f, 0.f, 0.f, 0.f);
    float4 o1 = make_float4(0.f, 0.f, 0.f, 0.f);
    for (int wt = 0; wt < 5; ++wt) {
        if (wt < 4) {
            const float4* src = ww4 + (size_t)(wt + 1) * 500;
            sA = src[t]; if (t < 244) sB = src[t + 256];
        }
        if (t < 200) {
            const float* wb = s_w[wt & 1];
            const int kb = wt * 20;
#pragma unroll 2
            for (int kk = 0; kk < 20; kk += 4) {
                float4 a0 = *(const float4*)&s_ax[(rg * 2 + 0) * 108 + kb + kk];
                float4 a1 = *(const float4*)&s_ax[(rg * 2 + 1) * 108 + kb + kk];
                float4 v0 = *(const float4*)&wb[(kk + 0) * 100 + c];
                float4 v1 = *(const float4*)&wb[(kk + 1) * 100 + c];
                float4 v2 = *(const float4*)&wb[(kk + 2) * 100 + c];
                float4 v3 = *(const float4*)&wb[(kk + 3) * 100 + c];
                fma4(o0, a0.x, v0); fma4(o0, a0.y, v1); fma4(o0, a0.z, v2); fma4(o0, a0.w, v3);
                fma4(o1, a1.x, v0); fma4(o1, a1.y, v1); fma4(o1, a1.z, v2); fma4(o1, a1.w, v3);
            }
        }
        if (wt < 4) {
            float4* d4 = (float4*)s_w[(wt + 1) & 1];
            d4[t] = sA; if (t < 244) d4[t + 256] = sB;
        }
        __syncthreads();
    }

    float* s_go = s_pool + 1728;
    if (t < 200) {
        float4 bias = *(const float4*)&W_b[c];
        o0.x = fmaxf(o0.x + bias.x, 0.f); o0.y = fmaxf(o0.y + bias.y, 0.f);
        o0.z = fmaxf(o0.z + bias.z, 0.f); o0.w = fmaxf(o0.w + bias.w, 0.f);
        o1.x = fmaxf(o1.x + bias.x, 0.f); o1.y = fmaxf(o1.y + bias.y, 0.f);
        o1.z = fmaxf(o1.z + bias.z, 0.f); o1.w = fmaxf(o1.w + bias.w, 0.f);
        *(float4*)&go1[(size_t)(b * CL + i0 + rg * 2 + 0) * CATT + c] = o0;
        *(float4*)&go1[(size_t)(b * CL + i0 + rg * 2 + 1) * CATT + c] = o1;
        *(float4*)&s_go[(rg * 2 + 0) * 104 + c] = o0;
        *(float4*)&s_go[(rg * 2 + 1) * 104 + c] = o1;
    }
    __syncthreads();

    if (t < 128) {
        int r = t >> 3, seg = t & 7;
        int e0 = seg * 13, e1 = e0 + 13 < 100 ? e0 + 13 : 100;
        float a = 0.f, c2 = 0.f;
        for (int e = e0; e < e1; ++e) {
            float v = s_go[r * 104 + e];
            a = fmaf(v, s_w1[e], a);
            c2 = fmaf(v, s_w2[e], c2);
        }
        a += __shfl_xor(a, 1); a += __shfl_xor(a, 2); a += __shfl_xor(a, 4);
        c2 += __shfl_xor(c2, 1); c2 += __shfl_xor(c2, 2); c2 += __shfl_xor(c2, 4);
        if (seg == 0) {
            s_g1row[r] = a;
            gW2S[b * CL + i0 + r] = c2;
        }
    }
    __syncthreads();

    if (t < 100) {   // deterministic t1/t2 partials for this chunk
        float a = 0.f, s2 = 0.f;
#pragma unroll
        for (int r = 0; r < 16; ++r) {
            float v = s_go[r * 104 + t];
            a = fmaf(s_g1row[r], v, a);
            s2 += v;
        }
        float* dst = t12_part + (size_t)(b * 16 + ic) * 200;
        dst[t] = a;
        dst[100 + t] = s2;
    }
}

// ---------------------------------------------------------------------------
// k7: GCN1 + rank-1 corrections (t1/t2 reduced from partials) + masked
// pooling -> deterministic out1_part (no atomics).
// ---------------------------------------------------------------------------
__global__ __launch_bounds__(256, 3) void k7_gcn1(
    const float* __restrict__ adjW, const float* __restrict__ go1,
    const float* __restrict__ W_w, const float* __restrict__ W_b,
    const float* __restrict__ t12_part, const float* __restrict__ gW2S,
    const float* __restrict__ Wx_b, const float* __restrict__ amask,
    float* __restrict__ out1_part)
{
    __shared__ float s_pool[16 * 260];
    __shared__ float s_w[2][3200];
    __shared__ float s_t1[100], s_t2[100];
    const int b = blockIdx.x >> 4, ic = blockIdx.x & 15;
    const int i0 = ic * 16;
    const int t = threadIdx.x;

    {
        const float4* asrc = (const float4*)adjW + (size_t)(b * CL + i0) * 64;
#pragma unroll
        for (int m = 0; m < 4; ++m) {
            int i = t + 256 * m;
            int row = i >> 6, c4 = i & 63;
            *(float4*)&s_pool[row * 260 + c4 * 4] = asrc[i];
        }
    }
    if (t < 100) {   // reduce t1/t2 partials (16 chunks)
        float a = 0.f, s2 = 0.f;
#pragma unroll
        for (int c2 = 0; c2 < 16; ++c2) {
            const float* src = t12_part + (size_t)(b * 16 + c2) * 200;
            a += src[t];
            s2 += src[100 + t];
        }
        s_t1[t] = a; s_t2[t] = s2;
    }
    const int cg2 = t % 25, rg = t / 25;
    const int c = cg2 * 4;
    const float4* g4 = (const float4*)go1 + (size_t)b * 6400;
    float4 sA = g4[t], sB = g4[t + 256], sC = g4[t + 512], sD;
    if (t < 32) sD = g4[t + 768];
    {
        float4* d4 = (float4*)s_w[0];
        d4[t] = sA; d4[t + 256] = sB; d4[t + 512] = sC;
        if (t < 32) d4[t + 768] = sD;
    }
    __syncthreads();

    float4 acc0 = make_float4(0.f, 0.f, 0.f, 0.f);
    float4 acc1 = make_float4(0.f, 0.f, 0.f, 0.f);
    for (int jt = 0; jt < 8; ++jt) {
        if (jt < 7) {
            const float4* src = g4 + (size_t)(jt + 1) * 800;
            sA = src[t]; sB = src[t + 256]; sC = src[t + 512];
            if (t < 32) sD = src[t + 768];
        }
        if (t < 200) {
            const float* wb = s_w[jt & 1];
#pragma unroll 2
            for (int kk = 0; kk < 32; kk += 4) {
                float4 a0 = *(const float4*)&s_pool[(rg * 2 + 0) * 260 + jt * 32 + kk];
                float4 a1 = *(const float4*)&s_pool[(rg * 2 + 1) * 260 + jt * 32 + kk];
                float4 v0 = *(const float4*)&wb[(kk + 0) * 100 + c];
                float4 v1 = *(const float4*)&wb[(kk + 1) * 100 + c];
                float4 v2 = *(const float4*)&wb[(kk + 2) * 100 + c];
                float4 v3 = *(const float4*)&wb[(kk + 3) * 100 + c];
                fma4(acc0, a0.x, v0); fma4(acc0, a0.y, v1); fma4(acc0, a0.z, v2); fma4(acc0, a0.w, v3);
                fma4(acc1, a1.x, v0); fma4(acc1, a1.y, v1); fma4(acc1, a1.z, v2); fma4(acc1, a1.w, v3);
            }
        }
        if (jt < 7) {
            float4* d4 = (float4*)s_w[(jt + 1) & 1];
            d4[t] = sA; d4[t + 256] = sB; d4[t + 512] = sC;
            if (t < 32) d4[t + 768] = sD;
        }
        __syncthreads();
    }

    float* s_ax = s_pool;
    if (t < 200) {
        float wxbs = Wx_b[0] + Wx_b[1] + Wx_b[2] + Wx_b[3] + Wx_b[4];
        float4 t1v = *(const float4*)&s_t1[c];
        float4 t2v = *(const float4*)&s_t2[c];
        float gw0 = gW2S[b * CL + i0 + rg * 2 + 0] + wxbs;
        float gw1 = gW2S[b * CL + i0 + rg * 2 + 1] + wxbs;
        float4 r;
        r.x = (acc0.x + t1v.x + gw0 * t2v.x) * 0.2f;
        r.y = (acc0.y + t1v.y + gw0 * t2v.y) * 0.2f;
        r.z = (acc0.z + t1v.z + gw0 * t2v.z) * 0.2f;
        r.w = (acc0.w + t1v.w + gw0 * t2v.w) * 0.2f;
        *(float4*)&s_ax[(rg * 2 + 0) * 108 + c] = r;
        r.x = (acc1.x + t1v.x + gw1 * t2v.x) * 0.2f;
        r.y = (acc1.y + t1v.y + gw1 * t2v.y) * 0.2f;
        r.z = (acc1.z + t1v.z + gw1 * t2v.z) * 0.2f;
        r.w = (acc1.w + t1v.w + gw1 * t2v.w) * 0.2f;
        *(float4*)&s_ax[(rg * 2 + 1) * 108 + c] = r;
    }
    const float4* ww4 = (const float4*)W_w;
    sA = ww4[t]; if (t < 244) sB = ww4[t + 256];
    {
        float4* d4 = (float4*)s_w[0];
        d4[t] = sA; if (t < 244) d4[t + 256] = sB;
    }
    __syncthreads();

    float4 o0 = make_float4(0.f, 0.f, 0.f, 0.f);
    float4 o1 = make_float4(0.f, 0.f, 0.f, 0.f);
    for (int wt = 0; wt < 5; ++wt) {
        if (wt < 4) {
            const float4* src = ww4 + (size_t)(wt + 1) * 500;
            sA = src[t]; if (t < 244) sB = src[t + 256];
        }
        if (t < 200) {
            const float* wb = s_w[wt & 1];
            const int kb = wt * 20;
#pragma unroll 2
            for (int kk = 0; kk < 20; kk += 4) {
                float4 a0 = *(const float4*)&s_ax[(rg * 2 + 0) * 108 + kb + kk];
                float4 a1 = *(const float4*)&s_ax[(rg * 2 + 1) * 108 + kb + kk];
                float4 v0 = *(const float4*)&wb[(kk + 0) * 100 + c];
                float4 v1 = *(const float4*)&wb[(kk + 1) * 100 + c];
                float4 v2 = *(const float4*)&wb[(kk + 2) * 100 + c];
                float4 v3 = *(const float4*)&wb[(kk + 3) * 100 + c];
                fma4(o0, a0.x, v0); fma4(o0, a0.y, v1); fma4(o0, a0.z, v2); fma4(o0, a0.w, v3);
                fma4(o1, a1.x, v0); fma4(o1, a1.y, v1); fma4(o1, a1.z, v2); fma4(o1, a1.w, v3);
            }
        }
        if (wt < 4) {
            float4* d4 = (float4*)s_w[(wt + 1) & 1];
            d4[t] = sA; if (t < 244) d4[t + 256] = sB;
        }
        __syncthreads();
    }

    // masked pooled partials (deterministic)
    float* s_part = s_pool + 1728;   // 8 x 100
    if (t < 200) {
        float4 bias = *(const float4*)&W_b[c];
        o0.x = fmaxf(o0.x + bias.x, 0.f); o0.y = fmaxf(o0.y + bias.y, 0.f);
        o0.z = fmaxf(o0.z + bias.z, 0.f); o0.w = fmaxf(o0.w + bias.w, 0.f);
        o1.x = fmaxf(o1.x + bias.x, 0.f); o1.y = fmaxf(o1.y + bias.y, 0.f);
        o1.z = fmaxf(o1.z + bias.z, 0.f); o1.w = fmaxf(o1.w + bias.w, 0.f);
        float m0 = amask[b * CL + i0 + rg * 2 + 0];
        float m1 = amask[b * CL + i0 + rg * 2 + 1];
        float4 pr;
        pr.x = m0 * o0.x + m1 * o1.x;
        pr.y = m0 * o0.y + m1 * o1.y;
        pr.z = m0 * o0.z + m1 * o1.z;
        pr.w = m0 * o0.w + m1 * o1.w;
        *(float4*)&s_part[rg * 100 + c] = pr;
    }
    __syncthreads();
    if (t < 100) {
        float s2 = 0.f;
#pragma unroll
        for (int r = 0; r < 8; ++r) s2 += s_part[r * 100 + t];
        out1_part[(size_t)(b * 16 + ic) * CATT + t] = s2;
    }
}

// ---------------------------------------------------------------------------
// k8: reduce out1 partials, divide by wn, classifier.
// ---------------------------------------------------------------------------
__global__ __launch_bounds__(128) void k8_small(
    const float* __restrict__ out1_part, const float* __restrict__ amask,
    const float* __restrict__ clf_w, const float* __restrict__ clf_b,
    float* __restrict__ out)
{
    __shared__ float s_o[100];
    __shared__ float s_wn;
    const int b = blockIdx.x, t = threadIdx.x;
    if (t < 64) {
        float4 mv = ((const float4*)amask)[b * 64 + t];
        float wn = mv.x + mv.y + mv.z + mv.w;
#pragma unroll
        for (int o = 32; o; o >>= 1) wn += __shfl_xor(wn, o);
        if (t == 0) s_wn = wn;
    }
    __syncthreads();
    if (t < 100) {
        float s2 = 0.f;
#pragma unroll
        for (int c2 = 0; c2 < 16; ++c2)
            s2 += out1_part[(size_t)(b * 16 + c2) * CATT + t];
        s_o[t] = s2 / s_wn;
    }
    __syncthreads();
    if (t < 3) {
        float a = clf_b[t];
        for (int d = 0; d < CATT; ++d)
            a = fmaf(s_o[d], clf_w[d * 3 + t], a);
        out[b * 3 + t] = a;
    }
}

// ---------------------------------------------------------------------------
extern "C" void kernel_launch(void* const* d_in, const int* in_sizes, int n_in,
                              void* d_out, int out_size, void* d_ws, size_t ws_size,
                              hipStream_t stream) {
    const float* seq     = (const float*)d_in[0];
    const int*   srcm    = (const int*)d_in[1];
    const float* amask   = (const float*)d_in[2];
    const float* shortm  = (const float*)d_in[3];
    const float* ln_a    = (const float*)d_in[4];
    const float* ln_b    = (const float*)d_in[5];
    const float* Wxx_w   = (const float*)d_in[6];
    const float* Wxx_b   = (const float*)d_in[7];
    const float* q_w     = (const float*)d_in[8];
    const float* q_b     = (const float*)d_in[9];
    const float* k_w     = (const float*)d_in[10];
    const float* k_b     = (const float*)d_in[11];
    const float* dense_w = (const float*)d_in[12];
    const float* dense_b = (const float*)d_in[13];
    const float* bias_m  = (const float*)d_in[14];
    const float* W_w     = (const float*)d_in[15];
    const float* W_b     = (const float*)d_in[16];
    const float* Wx_w    = (const float*)d_in[17];
    const float* Wx_b    = (const float*)d_in[18];
    const float* clf_w   = (const float*)d_in[19];
    const float* clf_b   = (const float*)d_in[20];
    float* out = (float*)d_out;

    float* ws        = (float*)d_ws;
    float* g         = ws;                    // 819200
    float* qt        = g + 819200;            // 819200
    float* ktb       = qt + 819200;           // 819200
    float* go1       = ktb + 819200;          // 819200
    float* adjW      = go1 + 819200;          // 2097152
    float* gW2S      = adjW + 2097152;        // 8192
    float* t12_part  = gW2S + 8192;           // 102400
    float* out1_part = t12_part + 102400;     // 51200

    // No zero-init required: all reductions are deterministic partial stores.
    hipLaunchKernelGGL(k1_fused, dim3(512), dim3(256), 0, stream, seq, ln_a, ln_b,
                       Wxx_w, Wxx_b, q_w, q_b, k_w, k_b, g, qt, ktb);
    hipLaunchKernelGGL(k45_attn_gcn0, dim3(512), dim3(256), 0, stream,
                       qt, ktb, amask, dense_w, dense_b, bias_m, srcm,
                       shortm, Wx_w, g, W_w, W_b, adjW, go1, t12_part, gW2S);
    hipLaunchKernelGGL(k7_gcn1, dim3(512), dim3(256), 0, stream,
                       adjW, go1, W_w, W_b, t12_part, gW2S, Wx_b, amask, out1_part);
    hipLaunchKernelGGL(k8_small, dim3(32), dim3(128), 0, stream,
                       out1_part, amask, clf_w, clf_b, out);
}